// Round 5
// baseline (539.592 us; speedup 1.0000x reference)
//
#include <hip/hip_runtime.h>
#include <hip/hip_bf16.h>
#include <stdint.h>

#define N_PTS 100000
#define INC 128
#define NSLOT 27
#define CAPP 8192    // pair capacity per slot (expected ~620)
#define CAPA 16384   // compact aux rows (expected ~2.4k multi cells)
#define CAPD 32768   // compact dst rows (expected ~15k)

typedef float f32x4 __attribute__((ext_vector_type(4)));
typedef short bf16x8 __attribute__((ext_vector_type(8)));

// ---------------- workspace layout --------------------------------------
static const size_t OFF_WP   = 0;                                        // 27 slots frag-packed bf16
static const size_t SZ_WP    = (size_t)NSLOT * INC * INC * 2;
static const size_t OFF_WPRE = (OFF_WP + SZ_WP + 255) & ~(size_t)255;    // w_pre frag-packed bf16
static const size_t SZ_WPRE  = (size_t)INC * INC * 2;
static const size_t OFF_FIN  = (OFF_WPRE + SZ_WPRE + 255) & ~(size_t)255; // F_input bf16
static const size_t SZ_FIN   = (size_t)N_PTS * INC * 2;
static const size_t OFF_LOC  = (OFF_FIN + SZ_FIN + 255) & ~(size_t)255;   // self-local bf16
static const size_t SZ_LOC   = (size_t)N_PTS * INC * 2;
static const size_t OFF_RMP  = (OFF_LOC + SZ_LOC + 255) & ~(size_t)255;   // cell -> aux id
static const size_t SZ_RMP   = (size_t)N_PTS * 4;
static const size_t OFF_RMP2 = (OFF_RMP + SZ_RMP + 255) & ~(size_t)255;   // point -> dst id
static const size_t SZ_RMP2  = (size_t)N_PTS * 4;
static const size_t OFF_AUXC = (OFF_RMP2 + SZ_RMP2 + 255) & ~(size_t)255; // compact aux rows f32
static const size_t SZ_AUXC  = (size_t)CAPA * 3 * INC * 4;
static const size_t OFF_SPC  = (OFF_AUXC + SZ_AUXC + 255) & ~(size_t)255; // compact sparse acc f32
static const size_t SZ_SPC   = (size_t)CAPD * INC * 4;
static const size_t OFF_CNT  = (OFF_SPC + SZ_SPC + 255) & ~(size_t)255;   // 26 pair ctrs + aux + dst
static const size_t SZ_CNT   = 128;
static const size_t OFF_DST  = (OFF_CNT + SZ_CNT + 255) & ~(size_t)255;
static const size_t SZ_DST   = (size_t)26 * CAPP * 4;
static const size_t OFF_SRC  = (OFF_DST + SZ_DST + 255) & ~(size_t)255;
static const size_t SZ_SRC   = (size_t)26 * CAPP * 4;   // total ~96 MB

// identical in all kernels so the vox2 - F_input*pos cancellation stays ~exact
__device__ __forceinline__ float compute_pos(int c, float cx, float cy, float cz,
                                             const float* __restrict__ w_pos,
                                             const float* __restrict__ alpha) {
    const float* w = w_pos + c * 3;
    return (cx * w[0] + cy * w[1] + cz * w[2]) * alpha[c];
}

// load 8 consecutive f32 and round to a bf16x8 MFMA fragment
__device__ __forceinline__ bf16x8 ld_cvt8(const float* __restrict__ p) {
    const float4 u = *(const float4*)p;
    const float4 v = *(const float4*)(p + 4);
    bf16x8 r;
    __hip_bfloat16* h = (__hip_bfloat16*)&r;
    h[0] = __float2bfloat16(u.x); h[1] = __float2bfloat16(u.y);
    h[2] = __float2bfloat16(u.z); h[3] = __float2bfloat16(u.w);
    h[4] = __float2bfloat16(v.x); h[5] = __float2bfloat16(v.y);
    h[6] = __float2bfloat16(v.z); h[7] = __float2bfloat16(v.w);
    return r;
}

// ---------------- K_prep: zero flags/counters + pack weights ----------------
// Fragment packing: lane (q=lane>>4,l15=lane&15) of frag (slot,ks,j) holds
// B[n=j*16+l15][k=ks*32+q*8+i], i=0..7 -> one wave-load = one 1KB burst.
__global__ __launch_bounds__(256) void k_prep(
        const float* __restrict__ w_pre, const float* __restrict__ w_conv,
        __hip_bfloat16* __restrict__ Wp, __hip_bfloat16* __restrict__ Wpre,
        int* __restrict__ rmp, int* __restrict__ rmp2, int* __restrict__ cnt) {
    int i = blockIdx.x * 256 + threadIdx.x;
    if (i < N_PTS) { rmp[i] = 0; rmp2[i] = 0; }
    if (i < 32) cnt[i] = 0;
    if (i < 16384) {                      // w_pre pack: B[n=d][k=c] = w_pre[d][c]
        int j = i;
        int ii = j & 7, lane = (j >> 3) & 63, jj = (j >> 9) & 7, ks = (j >> 12) & 3;
        int l15 = lane & 15, qq = lane >> 4;
        int d = jj * 16 + l15, c = ks * 32 + qq * 8 + ii;
        Wpre[j] = __float2bfloat16(w_pre[d * INC + c]);
    } else if (i < 16384 + NSLOT * 16384) {  // w_conv pack: B[n=d][k=c] = w_conv[slot][c][d]
        int j = i - 16384;
        int ii = j & 7, lane = (j >> 3) & 63, jj = (j >> 9) & 7, ks = (j >> 12) & 3;
        int slot = j >> 14;
        int l15 = lane & 15, qq = lane >> 4;
        int c = ks * 32 + qq * 8 + ii, d = jj * 16 + l15;
        Wp[j] = __float2bfloat16(w_conv[(size_t)slot * INC * INC + (size_t)c * INC + d]);
    }
}

// ---------------- K_scan: pair lists + multi-cell flags + dst flags ---------
__global__ __launch_bounds__(256) void k_scan(
        const int* __restrict__ nbr_idx, const float* __restrict__ counts_v,
        const int* __restrict__ aux_idx, int* __restrict__ rmp, int* __restrict__ rmp2,
        int* __restrict__ cnt, int* __restrict__ dst, int* __restrict__ src) {
    int p = blockIdx.x * 256 + threadIdx.x;
    if (p >= N_PTS) return;
    if (counts_v[p] > 1.5f) rmp[aux_idx[p]] = 1;   // benign race: all write 1
    const int* nb = nbr_idx + (size_t)p * NSLOT;
    int any = 0;
#pragma unroll
    for (int k = 0; k < NSLOT; ++k) {
        if (k == 13) continue;                     // self handled densely
        int m = nb[k];
        if (m < N_PTS) {
            any = 1;
            int b = k < 13 ? k : k - 1;            // 0..25
            int idx = atomicAdd(&cnt[b], 1);
            if (idx < CAPP) { dst[b * CAPP + idx] = p; src[b * CAPP + idx] = m; }
        }
    }
    if (any) rmp2[p] = 1;
}

// ---------------- K_assign: compact ids + zero their accumulator rows -------
__global__ __launch_bounds__(256) void k_assign(
        int* __restrict__ rmp, int* __restrict__ rmp2, int* __restrict__ cnt,
        float* __restrict__ auxc, float* __restrict__ spacc) {
    int c = blockIdx.x * 256 + threadIdx.x;
    if (c >= N_PTS) return;
    if (rmp[c] == 1) {
        int id = atomicAdd(&cnt[26], 1);
        if (id < CAPA) {
            rmp[c] = id + 2;
            float4* row = (float4*)(auxc + (size_t)id * (3 * INC));
#pragma unroll
            for (int i = 0; i < (3 * INC) / 4; ++i) row[i] = make_float4(0.f, 0.f, 0.f, 0.f);
        } else rmp[c] = 0;
    }
    if (rmp2[c] == 1) {
        int id = atomicAdd(&cnt[27], 1);
        if (id < CAPD) {
            rmp2[c] = id + 2;
            float4* row = (float4*)(spacc + (size_t)id * INC);
#pragma unroll
            for (int i = 0; i < INC / 4; ++i) row[i] = make_float4(0.f, 0.f, 0.f, 0.f);
        } else rmp2[c] = 0;
    }
}

// ---------------- K1: fused dual GEMM (pre_mix + dense self-slot conv) ------
// Reads F (f32) directly, converts fragments in-reg. Writes bf16 F_input/loc.
__global__ __launch_bounds__(256) void k_pre_gemm(
        const float* __restrict__ F, const __hip_bfloat16* __restrict__ Wpre,
        const __hip_bfloat16* __restrict__ Wp, const int* __restrict__ coords,
        const float* __restrict__ counts_v, const int* __restrict__ aux_idx,
        const int* __restrict__ rmp, const float* __restrict__ w_pos,
        const float* __restrict__ alpha, const float* __restrict__ g_pre,
        const float* __restrict__ b_pre, __hip_bfloat16* __restrict__ F_input,
        __hip_bfloat16* __restrict__ loc, float* __restrict__ auxc) {
    const int tid = threadIdx.x, w = tid >> 6, lane = tid & 63;
    const int q = lane >> 4, l15 = lane & 15;
    const int p0 = blockIdx.x * 128;

    int grow0 = p0 + (w << 5) + l15;
    int grow1 = grow0 + 16;
    if (grow0 >= N_PTS) grow0 = N_PTS - 1;   // clamp; epilogue skips invalid p
    if (grow1 >= N_PTS) grow1 = N_PTS - 1;

    const float* A0 = F + (size_t)grow0 * INC + q * 8;
    const float* A1 = F + (size_t)grow1 * INC + q * 8;
    const bf16x8* BpP = (const bf16x8*)Wpre;
    const bf16x8* BpL = (const bf16x8*)Wp + (size_t)13 * 2048;   // self slot

    f32x4 accP[2][8], accL[2][8];
#pragma unroll
    for (int i = 0; i < 2; ++i)
#pragma unroll
        for (int j = 0; j < 8; ++j) {
            accP[i][j] = (f32x4){0.f, 0.f, 0.f, 0.f};
            accL[i][j] = (f32x4){0.f, 0.f, 0.f, 0.f};
        }

#pragma unroll
    for (int ks = 0; ks < 4; ++ks) {
        bf16x8 a0 = ld_cvt8(A0 + ks * 32);
        bf16x8 a1 = ld_cvt8(A1 + ks * 32);
        bf16x8 bP[8], bL[8];
#pragma unroll
        for (int j = 0; j < 8; ++j) { bP[j] = BpP[(ks * 8 + j) * 64 + lane]; bL[j] = BpL[(ks * 8 + j) * 64 + lane]; }
#pragma unroll
        for (int j = 0; j < 8; ++j) {
            accP[0][j] = __builtin_amdgcn_mfma_f32_16x16x32_bf16(a0, bP[j], accP[0][j], 0, 0, 0);
            accP[1][j] = __builtin_amdgcn_mfma_f32_16x16x32_bf16(a1, bP[j], accP[1][j], 0, 0, 0);
            accL[0][j] = __builtin_amdgcn_mfma_f32_16x16x32_bf16(a0, bL[j], accL[0][j], 0, 0, 0);
            accL[1][j] = __builtin_amdgcn_mfma_f32_16x16x32_bf16(a1, bL[j], accL[1][j], 0, 0, 0);
        }
    }

    // epilogue: LN -> bf16 F_input (and use the ROUNDED value for aux atomics
    // so the final-kernel cancellation is consistent); self-local -> bf16 loc
#pragma unroll
    for (int i = 0; i < 2; ++i) {
#pragma unroll
        for (int r = 0; r < 4; ++r) {
            int p = p0 + (w << 5) + (i << 4) + (q << 2) + r;
            if (p >= N_PTS) continue;
            float vj[8], s = 0.f, ss = 0.f;
#pragma unroll
            for (int j = 0; j < 8; ++j) { float v = accP[i][j][r]; vj[j] = v; s += v; ss += v * v; }
#pragma unroll
            for (int m = 1; m < 16; m <<= 1) { s += __shfl_xor(s, m); ss += __shfl_xor(ss, m); }
            float mean = s * (1.f / 128.f);
            float rstd = rsqrtf(ss * (1.f / 128.f) - mean * mean + 1e-6f);
            int rid = 0;
            bool multi = counts_v[p] > 1.5f && (rid = rmp[aux_idx[p]]) >= 2;
            float cx = (float)coords[p * 3 + 0], cy = (float)coords[p * 3 + 1],
                  cz = (float)coords[p * 3 + 2];
            float* auxp = auxc + (size_t)(rid - 2) * (3 * INC);
#pragma unroll
            for (int j = 0; j < 8; ++j) {
                int c = (j << 4) + l15;
                float fi = (vj[j] - mean) * rstd * g_pre[c] + b_pre[c];
                __hip_bfloat16 fb = __float2bfloat16(fi);
                F_input[(size_t)p * INC + c] = fb;
                loc[(size_t)p * INC + c] = __float2bfloat16(accL[i][j][r]);
                if (multi) {
                    float fr = __bfloat162float(fb);
                    float ps = compute_pos(c, cx, cy, cz, w_pos, alpha);
                    float sn, cs; sincosf(ps, &sn, &cs);
                    atomicAdd(auxp + c,           fr * cs);
                    atomicAdd(auxp + INC + c,     fr * sn);
                    atomicAdd(auxp + 2 * INC + c, fr * ps);
                }
            }
        }
    }
}

// ---------------- K_sparse: pair GEMM, scatter into compact spacc -----------
__global__ __launch_bounds__(64) void k_sparse(
        const float* __restrict__ F, const __hip_bfloat16* __restrict__ Wp,
        const int* __restrict__ cnt, const int* __restrict__ dst,
        const int* __restrict__ src, const int* __restrict__ rmp2,
        float* __restrict__ spacc) {
    const int b = blockIdx.x >> 7;          // bucket 0..25
    const int chunk = blockIdx.x & 127;
    int n = cnt[b]; if (n > CAPP) n = CAPP;
    const int base = chunk * 64;
    if (base >= n) return;
    const int slot = b < 13 ? b : b + 1;

    const int lane = threadIdx.x & 63;
    const int q = lane >> 4, l15 = lane & 15;
    const int* srcb = src + b * CAPP;
    const int* dstb = dst + b * CAPP;

    int m[4];
#pragma unroll
    for (int i = 0; i < 4; ++i) {
        int ri = base + i * 16 + l15;
        m[i] = (ri < n) ? srcb[ri] : N_PTS;
    }
    const bf16x8* Bp = (const bf16x8*)Wp + (size_t)slot * 2048;

    f32x4 acc[4][8];
#pragma unroll
    for (int i = 0; i < 4; ++i)
#pragma unroll
        for (int j = 0; j < 8; ++j) acc[i][j] = (f32x4){0.f, 0.f, 0.f, 0.f};

#pragma unroll
    for (int ks = 0; ks < 4; ++ks) {
        bf16x8 a[4];
#pragma unroll
        for (int i = 0; i < 4; ++i) {
            int rr = m[i] < N_PTS ? m[i] : 0;
            bf16x8 av = ld_cvt8(F + (size_t)rr * INC + ks * 32 + q * 8);
            if (m[i] >= N_PTS) av = (bf16x8){0, 0, 0, 0, 0, 0, 0, 0};
            a[i] = av;
        }
        bf16x8 bb[8];
#pragma unroll
        for (int j = 0; j < 8; ++j) bb[j] = Bp[(ks * 8 + j) * 64 + lane];
#pragma unroll
        for (int j = 0; j < 8; ++j)
#pragma unroll
            for (int i = 0; i < 4; ++i)
                acc[i][j] = __builtin_amdgcn_mfma_f32_16x16x32_bf16(a[i], bb[j], acc[i][j], 0, 0, 0);
    }

    // scatter-add rows into compact spacc (dst id guaranteed flagged)
#pragma unroll
    for (int i = 0; i < 4; ++i) {
#pragma unroll
        for (int r = 0; r < 4; ++r) {
            int ri = base + i * 16 + (q << 2) + r;
            if (ri >= n) continue;
            int did = rmp2[dstb[ri]];
            if (did < 2) continue;              // overflow fallback
            float* lp = spacc + (size_t)(did - 2) * INC + l15;
#pragma unroll
            for (int j = 0; j < 8; ++j) atomicAdd(lp + (j << 4), acc[i][j][r]);
        }
    }
}

// ---------------- K_final: epilogue only (wide per-lane chunks) -------------
__global__ __launch_bounds__(256) void k_final(
        const __hip_bfloat16* __restrict__ F_input, const __hip_bfloat16* __restrict__ loc,
        const int* __restrict__ rmp, const int* __restrict__ rmp2,
        const float* __restrict__ auxc, const float* __restrict__ spacc,
        const int* __restrict__ coords, const float* __restrict__ counts_v,
        const int* __restrict__ aux_idx, const float* __restrict__ w_pos,
        const float* __restrict__ alpha, const float* __restrict__ g_local,
        const float* __restrict__ b_local, const float* __restrict__ g_norm,
        const float* __restrict__ b_norm, float* __restrict__ out) {
    const int tid = threadIdx.x, g = tid >> 4, l15 = tid & 15;
    const int c0 = l15 * 8;                 // this lane's 8 consecutive channels
    const int p0 = blockIdx.x * 128;
#pragma unroll 1
    for (int t = 0; t < 8; ++t) {
        int p = p0 + t * 16 + g;
        if (p >= N_PTS) continue;

        bf16x8 lb = *(const bf16x8*)(loc + (size_t)p * INC + c0);
        int did = rmp2[p];
        float lv[8], s = 0.f, ss = 0.f;
#pragma unroll
        for (int j = 0; j < 8; ++j) {
            float v = __bfloat162float(((__hip_bfloat16*)&lb)[j]);
            if (did >= 2) v += spacc[(size_t)(did - 2) * INC + c0 + j];
            lv[j] = v; s += v; ss += v * v;
        }
#pragma unroll
        for (int m = 1; m < 16; m <<= 1) { s += __shfl_xor(s, m); ss += __shfl_xor(ss, m); }
        float meanL = s * (1.f / 128.f);
        float rstdL = rsqrtf(ss * (1.f / 128.f) - meanL * meanL + 1e-6f);

        float cnt = counts_v[p];
        int rid = 0;
        bool multi = cnt > 1.5f && (rid = rmp[aux_idx[p]]) >= 2;
        float invc = 1.f / cnt;
        float cx = (float)coords[p * 3 + 0], cy = (float)coords[p * 3 + 1],
              cz = (float)coords[p * 3 + 2];
        const float* auxp = auxc + (size_t)(rid - 2) * (3 * INC);

        bf16x8 fbv = *(const bf16x8*)(F_input + (size_t)p * INC + c0);
        float nv[8], s2 = 0.f, ss2 = 0.f;
#pragma unroll
        for (int j = 0; j < 8; ++j) {
            int c = c0 + j;
            float f = __bfloat162float(((__hip_bfloat16*)&fbv)[j]);
            float ps = compute_pos(c, cx, cy, cz, w_pos, alpha);
            float sn, cs; sincosf(ps, &sn, &cs);
            float v0, v1, v2;
            if (multi) { v0 = auxp[c] * invc; v1 = auxp[INC + c] * invc; v2 = auxp[2 * INC + c] * invc; }
            else       { v0 = f * cs;         v1 = f * sn;               v2 = f * ps; }
            float nw = v0 * cs + v1 * sn + v2 - f * ps;   // singleton: exact cancel
            nv[j] = nw; s2 += nw; ss2 += nw * nw;
        }
#pragma unroll
        for (int m = 1; m < 16; m <<= 1) { s2 += __shfl_xor(s2, m); ss2 += __shfl_xor(ss2, m); }
        float meanN = s2 * (1.f / 128.f);
        float rstdN = rsqrtf(ss2 * (1.f / 128.f) - meanN * meanN + 1e-6f);
#pragma unroll
        for (int j = 0; j < 8; ++j) {
            int c = c0 + j;
            float nn = (nv[j] - meanN) * rstdN * g_norm[c] + b_norm[c];
            float ll = (lv[j] - meanL) * rstdL * g_local[c] + b_local[c];
            float o = nn + ll;
            out[(size_t)p * INC + c] = o > 0.f ? o : 0.f;
        }
    }
}

// ---------------- host launcher ---------------------------------------------
extern "C" void kernel_launch(void* const* d_in, const int* in_sizes, int n_in,
                              void* d_out, int out_size, void* d_ws, size_t ws_size,
                              hipStream_t stream) {
    (void)in_sizes; (void)n_in; (void)out_size; (void)ws_size;
    const float* F        = (const float*)d_in[0];
    const int*   coords   = (const int*)d_in[1];
    const int*   nbr      = (const int*)d_in[2];
    const int*   aux_idx  = (const int*)d_in[3];
    const float* counts_v = (const float*)d_in[4];
    const float* alpha    = (const float*)d_in[6];
    const float* w_pos    = (const float*)d_in[7];
    const float* w_pre    = (const float*)d_in[8];
    const float* g_pre    = (const float*)d_in[9];
    const float* b_pre    = (const float*)d_in[10];
    const float* w_conv   = (const float*)d_in[11];
    const float* g_local  = (const float*)d_in[12];
    const float* b_local  = (const float*)d_in[13];
    const float* g_norm   = (const float*)d_in[14];
    const float* b_norm   = (const float*)d_in[15];
    float* out = (float*)d_out;

    char* ws = (char*)d_ws;
    __hip_bfloat16* Wp   = (__hip_bfloat16*)(ws + OFF_WP);
    __hip_bfloat16* Wpre = (__hip_bfloat16*)(ws + OFF_WPRE);
    __hip_bfloat16* F_input = (__hip_bfloat16*)(ws + OFF_FIN);
    __hip_bfloat16* loc     = (__hip_bfloat16*)(ws + OFF_LOC);
    int*   rmp   = (int*)(ws + OFF_RMP);
    int*   rmp2  = (int*)(ws + OFF_RMP2);
    float* auxc  = (float*)(ws + OFF_AUXC);
    float* spacc = (float*)(ws + OFF_SPC);
    int*   cnt   = (int*)(ws + OFF_CNT);
    int*   dstb  = (int*)(ws + OFF_DST);
    int*   srcb  = (int*)(ws + OFF_SRC);

    const int mt = (N_PTS + 127) / 128;   // 782
    const int prep_tot = 16384 + NSLOT * 16384;   // 458,752 (>= N_PTS)
    k_prep<<<(prep_tot + 255) / 256, 256, 0, stream>>>(w_pre, w_conv, Wp, Wpre, rmp, rmp2, cnt);
    k_scan<<<(N_PTS + 255) / 256, 256, 0, stream>>>(nbr, counts_v, aux_idx, rmp, rmp2, cnt, dstb, srcb);
    k_assign<<<(N_PTS + 255) / 256, 256, 0, stream>>>(rmp, rmp2, cnt, auxc, spacc);
    k_pre_gemm<<<mt, 256, 0, stream>>>(F, Wpre, Wp, coords, counts_v, aux_idx, rmp,
                                       w_pos, alpha, g_pre, b_pre, F_input, loc, auxc);
    k_sparse<<<26 * 128, 64, 0, stream>>>(F, Wp, cnt, dstb, srcb, rmp2, spacc);
    k_final<<<mt, 256, 0, stream>>>(F_input, loc, rmp, rmp2, auxc, spacc, coords, counts_v,
                                    aux_idx, w_pos, alpha, g_local, b_local, g_norm, b_norm, out);
}

// Round 6
// 503.048 us; speedup vs baseline: 1.0726x; 1.0726x over previous
//
#include <hip/hip_runtime.h>
#include <hip/hip_bf16.h>
#include <stdint.h>

#define N_PTS 100000
#define INC 128
#define NSLOT 27
#define CAPP 8192    // pair capacity per slot (expected ~620)
#define CAPA 16384   // compact aux rows (expected ~2.4k multi cells)
#define CAPD 32768   // compact dst rows (expected ~15k)

typedef float f32x4 __attribute__((ext_vector_type(4)));
typedef short bf16x8 __attribute__((ext_vector_type(8)));

// ---------------- workspace layout --------------------------------------
static const size_t OFF_WP   = 0;                                        // 27 slots frag-packed bf16
static const size_t SZ_WP    = (size_t)NSLOT * INC * INC * 2;
static const size_t OFF_WPRE = (OFF_WP + SZ_WP + 255) & ~(size_t)255;    // w_pre frag-packed bf16
static const size_t SZ_WPRE  = (size_t)INC * INC * 2;
static const size_t OFF_FIN  = (OFF_WPRE + SZ_WPRE + 255) & ~(size_t)255; // F_input bf16
static const size_t SZ_FIN   = (size_t)N_PTS * INC * 2;
static const size_t OFF_LOC  = (OFF_FIN + SZ_FIN + 255) & ~(size_t)255;   // self-local bf16
static const size_t SZ_LOC   = (size_t)N_PTS * INC * 2;
static const size_t OFF_RMP  = (OFF_LOC + SZ_LOC + 255) & ~(size_t)255;   // cell -> aux id
static const size_t SZ_RMP   = (size_t)N_PTS * 4;
static const size_t OFF_RMP2 = (OFF_RMP + SZ_RMP + 255) & ~(size_t)255;   // point -> dst id
static const size_t SZ_RMP2  = (size_t)N_PTS * 4;
static const size_t OFF_AUXC = (OFF_RMP2 + SZ_RMP2 + 255) & ~(size_t)255; // compact aux rows f32
static const size_t SZ_AUXC  = (size_t)CAPA * 3 * INC * 4;
static const size_t OFF_SPC  = (OFF_AUXC + SZ_AUXC + 255) & ~(size_t)255; // compact sparse acc f32
static const size_t SZ_SPC   = (size_t)CAPD * INC * 4;
static const size_t OFF_CNT  = (OFF_SPC + SZ_SPC + 255) & ~(size_t)255;   // 26 pair ctrs + aux + dst
static const size_t SZ_CNT   = 128;
static const size_t OFF_DST  = (OFF_CNT + SZ_CNT + 255) & ~(size_t)255;
static const size_t SZ_DST   = (size_t)26 * CAPP * 4;
static const size_t OFF_SRC  = (OFF_DST + SZ_DST + 255) & ~(size_t)255;
static const size_t SZ_SRC   = (size_t)26 * CAPP * 4;   // total ~96 MB

// identical in all kernels so the vox2 - F_input*pos cancellation stays ~exact
__device__ __forceinline__ float compute_pos3(float w0, float w1, float w2, float a,
                                              float cx, float cy, float cz) {
    return (cx * w0 + cy * w1 + cz * w2) * a;
}

// load 8 consecutive f32 and round to a bf16x8 MFMA fragment
__device__ __forceinline__ bf16x8 ld_cvt8(const float* __restrict__ p) {
    const float4 u = *(const float4*)p;
    const float4 v = *(const float4*)(p + 4);
    bf16x8 r;
    __hip_bfloat16* h = (__hip_bfloat16*)&r;
    h[0] = __float2bfloat16(u.x); h[1] = __float2bfloat16(u.y);
    h[2] = __float2bfloat16(u.z); h[3] = __float2bfloat16(u.w);
    h[4] = __float2bfloat16(v.x); h[5] = __float2bfloat16(v.y);
    h[6] = __float2bfloat16(v.z); h[7] = __float2bfloat16(v.w);
    return r;
}

// ---------------- K_prep: zero flags/counters + pack weights ----------------
__global__ __launch_bounds__(256) void k_prep(
        const float* __restrict__ w_pre, const float* __restrict__ w_conv,
        __hip_bfloat16* __restrict__ Wp, __hip_bfloat16* __restrict__ Wpre,
        int* __restrict__ rmp, int* __restrict__ rmp2, int* __restrict__ cnt) {
    int i = blockIdx.x * 256 + threadIdx.x;
    if (i < N_PTS) { rmp[i] = 0; rmp2[i] = 0; }
    if (i < 32) cnt[i] = 0;
    if (i < 16384) {                      // w_pre pack: B[n=d][k=c] = w_pre[d][c]
        int j = i;
        int ii = j & 7, lane = (j >> 3) & 63, jj = (j >> 9) & 7, ks = (j >> 12) & 3;
        int l15 = lane & 15, qq = lane >> 4;
        int d = jj * 16 + l15, c = ks * 32 + qq * 8 + ii;
        Wpre[j] = __float2bfloat16(w_pre[d * INC + c]);
    } else if (i < 16384 + NSLOT * 16384) {  // w_conv pack: B[n=d][k=c] = w_conv[slot][c][d]
        int j = i - 16384;
        int ii = j & 7, lane = (j >> 3) & 63, jj = (j >> 9) & 7, ks = (j >> 12) & 3;
        int slot = j >> 14;
        int l15 = lane & 15, qq = lane >> 4;
        int c = ks * 32 + qq * 8 + ii, d = jj * 16 + l15;
        Wp[j] = __float2bfloat16(w_conv[(size_t)slot * INC * INC + (size_t)c * INC + d]);
    }
}

// ---------------- K_scan: wave-aggregated pair-list build -------------------
__global__ __launch_bounds__(256) void k_scan(
        const int* __restrict__ nbr_idx, const float* __restrict__ counts_v,
        const int* __restrict__ aux_idx, int* __restrict__ rmp, int* __restrict__ rmp2,
        int* __restrict__ cnt, int* __restrict__ dst, int* __restrict__ src) {
    const int p = blockIdx.x * 256 + threadIdx.x;
    const int lane = threadIdx.x & 63;
    const bool vp = p < N_PTS;
    if (vp && counts_v[p] > 1.5f) rmp[aux_idx[p]] = 1;   // benign race: all write 1
    const int* nb = nbr_idx + (size_t)p * NSLOT;
    int any = 0;
#pragma unroll 1
    for (int k = 0; k < NSLOT; ++k) {
        if (k == 13) continue;                           // self handled densely
        int m = vp ? nb[k] : N_PTS;
        bool found = m < N_PTS;
        unsigned long long mask = __ballot(found);
        if (mask == 0ull) continue;
        int b = k < 13 ? k : k - 1;                      // 0..25
        int total = __popcll(mask);
        int base = 0;
        if (lane == 0) base = atomicAdd(&cnt[b], total); // one atomic per wave
        base = __shfl(base, 0);
        if (found) {
            any = 1;
            int idx = base + __popcll(mask & ((1ull << lane) - 1ull));
            if (idx < CAPP) { dst[b * CAPP + idx] = p; src[b * CAPP + idx] = m; }
        }
    }
    if (any) rmp2[p] = 1;
}

// ---------------- K_assign: compact ids + zero their accumulator rows -------
__global__ __launch_bounds__(256) void k_assign(
        int* __restrict__ rmp, int* __restrict__ rmp2, int* __restrict__ cnt,
        float* __restrict__ auxc, float* __restrict__ spacc) {
    int c = blockIdx.x * 256 + threadIdx.x;
    if (c >= N_PTS) return;
    if (rmp[c] == 1) {
        int id = atomicAdd(&cnt[26], 1);
        if (id < CAPA) {
            rmp[c] = id + 2;
            float4* row = (float4*)(auxc + (size_t)id * (3 * INC));
#pragma unroll
            for (int i = 0; i < (3 * INC) / 4; ++i) row[i] = make_float4(0.f, 0.f, 0.f, 0.f);
        } else rmp[c] = 0;
    }
    if (rmp2[c] == 1) {
        int id = atomicAdd(&cnt[27], 1);
        if (id < CAPD) {
            rmp2[c] = id + 2;
            float4* row = (float4*)(spacc + (size_t)id * INC);
#pragma unroll
            for (int i = 0; i < INC / 4; ++i) row[i] = make_float4(0.f, 0.f, 0.f, 0.f);
        } else rmp2[c] = 0;
    }
}

// ---------------- K1: fused dual GEMM (pre_mix + dense self-slot conv) ------
// Reads F (f32) directly. Stores bf16 F_input/loc via LDS transpose so every
// global write is a full-line 1KB-contiguous burst (no partial-line RMW).
__global__ __launch_bounds__(256) void k_pre_gemm(
        const float* __restrict__ F, const __hip_bfloat16* __restrict__ Wpre,
        const __hip_bfloat16* __restrict__ Wp, const int* __restrict__ coords,
        const float* __restrict__ counts_v, const int* __restrict__ aux_idx,
        const int* __restrict__ rmp, const float* __restrict__ w_pos,
        const float* __restrict__ alpha, const float* __restrict__ g_pre,
        const float* __restrict__ b_pre, __hip_bfloat16* __restrict__ F_input,
        __hip_bfloat16* __restrict__ loc, float* __restrict__ auxc) {
    __shared__ __hip_bfloat16 s_st[4][32][136];   // per-wave transpose buffer (+pad)
    __shared__ float s_gp[INC], s_bp[INC];

    const int tid = threadIdx.x, w = tid >> 6, lane = tid & 63;
    const int q = lane >> 4, l15 = lane & 15;
    const int p0 = blockIdx.x * 128;

    if (tid < INC) { s_gp[tid] = g_pre[tid]; s_bp[tid] = b_pre[tid]; }

    int grow0 = p0 + (w << 5) + l15;
    int grow1 = grow0 + 16;
    if (grow0 >= N_PTS) grow0 = N_PTS - 1;   // clamp; stores are guarded
    if (grow1 >= N_PTS) grow1 = N_PTS - 1;

    const float* A0 = F + (size_t)grow0 * INC + q * 8;
    const float* A1 = F + (size_t)grow1 * INC + q * 8;
    const bf16x8* BpP = (const bf16x8*)Wpre;
    const bf16x8* BpL = (const bf16x8*)Wp + (size_t)13 * 2048;   // self slot

    f32x4 accP[2][8], accL[2][8];
#pragma unroll
    for (int i = 0; i < 2; ++i)
#pragma unroll
        for (int j = 0; j < 8; ++j) {
            accP[i][j] = (f32x4){0.f, 0.f, 0.f, 0.f};
            accL[i][j] = (f32x4){0.f, 0.f, 0.f, 0.f};
        }

#pragma unroll
    for (int ks = 0; ks < 4; ++ks) {
        bf16x8 a0 = ld_cvt8(A0 + ks * 32);
        bf16x8 a1 = ld_cvt8(A1 + ks * 32);
        bf16x8 bP[8], bL[8];
#pragma unroll
        for (int j = 0; j < 8; ++j) { bP[j] = BpP[(ks * 8 + j) * 64 + lane]; bL[j] = BpL[(ks * 8 + j) * 64 + lane]; }
#pragma unroll
        for (int j = 0; j < 8; ++j) {
            accP[0][j] = __builtin_amdgcn_mfma_f32_16x16x32_bf16(a0, bP[j], accP[0][j], 0, 0, 0);
            accP[1][j] = __builtin_amdgcn_mfma_f32_16x16x32_bf16(a1, bP[j], accP[1][j], 0, 0, 0);
            accL[0][j] = __builtin_amdgcn_mfma_f32_16x16x32_bf16(a0, bL[j], accL[0][j], 0, 0, 0);
            accL[1][j] = __builtin_amdgcn_mfma_f32_16x16x32_bf16(a1, bL[j], accL[1][j], 0, 0, 0);
        }
    }
    __syncthreads();   // s_gp/s_bp ready

    // ---- phase 1: LN -> bf16 into LDS (per-wave region); aux atomics -------
#pragma unroll
    for (int i = 0; i < 2; ++i) {
#pragma unroll
        for (int r = 0; r < 4; ++r) {
            int ri = (i << 4) + (q << 2) + r;
            int p = p0 + (w << 5) + ri;
            float vj[8], s = 0.f, ss = 0.f;
#pragma unroll
            for (int j = 0; j < 8; ++j) { float v = accP[i][j][r]; vj[j] = v; s += v; ss += v * v; }
#pragma unroll
            for (int m = 1; m < 16; m <<= 1) { s += __shfl_xor(s, m); ss += __shfl_xor(ss, m); }
            float mean = s * (1.f / 128.f);
            float rstd = rsqrtf(ss * (1.f / 128.f) - mean * mean + 1e-6f);
            int rid = 0;
            bool multi = p < N_PTS && counts_v[p] > 1.5f && (rid = rmp[aux_idx[p]]) >= 2;
            float cx = 0.f, cy = 0.f, cz = 0.f;
            if (multi) {
                cx = (float)coords[p * 3 + 0]; cy = (float)coords[p * 3 + 1];
                cz = (float)coords[p * 3 + 2];
            }
            float* auxp = auxc + (size_t)(rid - 2) * (3 * INC);
#pragma unroll
            for (int j = 0; j < 8; ++j) {
                int c = (j << 4) + l15;
                float fi = (vj[j] - mean) * rstd * s_gp[c] + s_bp[c];
                __hip_bfloat16 fb = __float2bfloat16(fi);
                s_st[w][ri][c] = fb;
                if (multi) {
                    float fr = __bfloat162float(fb);
                    const float* wp = w_pos + c * 3;
                    float ps = compute_pos3(wp[0], wp[1], wp[2], alpha[c], cx, cy, cz);
                    float sn, cs; sincosf(ps, &sn, &cs);
                    atomicAdd(auxp + c,           fr * cs);
                    atomicAdd(auxp + INC + c,     fr * sn);
                    atomicAdd(auxp + 2 * INC + c, fr * ps);
                }
            }
        }
    }

    // ---- phase 2: read back lane-contiguous, wide store F_input ------------
#pragma unroll
    for (int t = 0; t < 8; ++t) {
        int row = (t << 2) + q;
        int p = p0 + (w << 5) + row;
        if (p < N_PTS) {
            bf16x8 v = *(const bf16x8*)&s_st[w][row][l15 * 8];
            *(bf16x8*)(F_input + (size_t)p * INC + l15 * 8) = v;
        }
    }

    // ---- phase 3: raw self-local into LDS ----------------------------------
#pragma unroll
    for (int i = 0; i < 2; ++i)
#pragma unroll
        for (int r = 0; r < 4; ++r) {
            int ri = (i << 4) + (q << 2) + r;
#pragma unroll
            for (int j = 0; j < 8; ++j)
                s_st[w][ri][(j << 4) + l15] = __float2bfloat16(accL[i][j][r]);
        }

    // ---- phase 4: wide store loc -------------------------------------------
#pragma unroll
    for (int t = 0; t < 8; ++t) {
        int row = (t << 2) + q;
        int p = p0 + (w << 5) + row;
        if (p < N_PTS) {
            bf16x8 v = *(const bf16x8*)&s_st[w][row][l15 * 8];
            *(bf16x8*)(loc + (size_t)p * INC + l15 * 8) = v;
        }
    }
}

// ---------------- K_sparse: pair GEMM, scatter into compact spacc -----------
__global__ __launch_bounds__(64) void k_sparse(
        const float* __restrict__ F, const __hip_bfloat16* __restrict__ Wp,
        const int* __restrict__ cnt, const int* __restrict__ dst,
        const int* __restrict__ src, const int* __restrict__ rmp2,
        float* __restrict__ spacc) {
    const int b = blockIdx.x >> 7;          // bucket 0..25
    const int chunk = blockIdx.x & 127;
    int n = cnt[b]; if (n > CAPP) n = CAPP;
    const int base = chunk * 64;
    if (base >= n) return;
    const int slot = b < 13 ? b : b + 1;

    const int lane = threadIdx.x & 63;
    const int q = lane >> 4, l15 = lane & 15;
    const int* srcb = src + b * CAPP;
    const int* dstb = dst + b * CAPP;

    int m[4];
#pragma unroll
    for (int i = 0; i < 4; ++i) {
        int ri = base + i * 16 + l15;
        m[i] = (ri < n) ? srcb[ri] : N_PTS;
    }
    const bf16x8* Bp = (const bf16x8*)Wp + (size_t)slot * 2048;

    f32x4 acc[4][8];
#pragma unroll
    for (int i = 0; i < 4; ++i)
#pragma unroll
        for (int j = 0; j < 8; ++j) acc[i][j] = (f32x4){0.f, 0.f, 0.f, 0.f};

#pragma unroll
    for (int ks = 0; ks < 4; ++ks) {
        bf16x8 a[4];
#pragma unroll
        for (int i = 0; i < 4; ++i) {
            int rr = m[i] < N_PTS ? m[i] : 0;
            bf16x8 av = ld_cvt8(F + (size_t)rr * INC + ks * 32 + q * 8);
            if (m[i] >= N_PTS) av = (bf16x8){0, 0, 0, 0, 0, 0, 0, 0};
            a[i] = av;
        }
        bf16x8 bb[8];
#pragma unroll
        for (int j = 0; j < 8; ++j) bb[j] = Bp[(ks * 8 + j) * 64 + lane];
#pragma unroll
        for (int j = 0; j < 8; ++j)
#pragma unroll
            for (int i = 0; i < 4; ++i)
                acc[i][j] = __builtin_amdgcn_mfma_f32_16x16x32_bf16(a[i], bb[j], acc[i][j], 0, 0, 0);
    }

#pragma unroll
    for (int i = 0; i < 4; ++i) {
#pragma unroll
        for (int r = 0; r < 4; ++r) {
            int ri = base + i * 16 + (q << 2) + r;
            if (ri >= n) continue;
            int did = rmp2[dstb[ri]];
            if (did < 2) continue;              // overflow fallback
            float* lp = spacc + (size_t)(did - 2) * INC + l15;
#pragma unroll
            for (int j = 0; j < 8; ++j) atomicAdd(lp + (j << 4), acc[i][j][r]);
        }
    }
}

// ---------------- K_final: epilogue only (per-lane contiguous channels) -----
__global__ __launch_bounds__(256) void k_final(
        const __hip_bfloat16* __restrict__ F_input, const __hip_bfloat16* __restrict__ loc,
        const int* __restrict__ rmp, const int* __restrict__ rmp2,
        const float* __restrict__ auxc, const float* __restrict__ spacc,
        const int* __restrict__ coords, const float* __restrict__ counts_v,
        const int* __restrict__ aux_idx, const float* __restrict__ w_pos,
        const float* __restrict__ alpha, const float* __restrict__ g_local,
        const float* __restrict__ b_local, const float* __restrict__ g_norm,
        const float* __restrict__ b_norm, float* __restrict__ out) {
    const int tid = threadIdx.x, g = tid >> 4, l15 = tid & 15;
    const int c0 = l15 * 8;                 // this lane's 8 consecutive channels
    const int p0 = blockIdx.x * 128;

    // hoisted, vectorized per-lane parameter loads
    float wpv[24], pa[8], gl[8], bl[8], gn[8], bn[8];
#pragma unroll
    for (int t = 0; t < 6; ++t) ((float4*)wpv)[t] = ((const float4*)(w_pos + c0 * 3))[t];
#pragma unroll
    for (int t = 0; t < 2; ++t) {
        ((float4*)pa)[t] = ((const float4*)(alpha   + c0))[t];
        ((float4*)gl)[t] = ((const float4*)(g_local + c0))[t];
        ((float4*)bl)[t] = ((const float4*)(b_local + c0))[t];
        ((float4*)gn)[t] = ((const float4*)(g_norm  + c0))[t];
        ((float4*)bn)[t] = ((const float4*)(b_norm  + c0))[t];
    }

#pragma unroll 1
    for (int t = 0; t < 8; ++t) {
        int p = p0 + t * 16 + g;
        if (p >= N_PTS) continue;

        bf16x8 lb = *(const bf16x8*)(loc + (size_t)p * INC + c0);
        int did = rmp2[p];
        float lv[8], s = 0.f, ss = 0.f;
#pragma unroll
        for (int j = 0; j < 8; ++j) {
            float v = __bfloat162float(((__hip_bfloat16*)&lb)[j]);
            if (did >= 2) v += spacc[(size_t)(did - 2) * INC + c0 + j];
            lv[j] = v; s += v; ss += v * v;
        }
#pragma unroll
        for (int m = 1; m < 16; m <<= 1) { s += __shfl_xor(s, m); ss += __shfl_xor(ss, m); }
        float meanL = s * (1.f / 128.f);
        float rstdL = rsqrtf(ss * (1.f / 128.f) - meanL * meanL + 1e-6f);

        float cnt = counts_v[p];
        int rid = 0;
        bool multi = cnt > 1.5f && (rid = rmp[aux_idx[p]]) >= 2;
        float invc = 1.f / cnt;
        float cx = (float)coords[p * 3 + 0], cy = (float)coords[p * 3 + 1],
              cz = (float)coords[p * 3 + 2];
        const float* auxp = auxc + (size_t)(rid - 2) * (3 * INC);

        bf16x8 fbv = *(const bf16x8*)(F_input + (size_t)p * INC + c0);
        float nv[8], s2 = 0.f, ss2 = 0.f;
#pragma unroll
        for (int j = 0; j < 8; ++j) {
            int c = c0 + j;
            float f = __bfloat162float(((__hip_bfloat16*)&fbv)[j]);
            float ps = compute_pos3(wpv[j * 3], wpv[j * 3 + 1], wpv[j * 3 + 2], pa[j], cx, cy, cz);
            float sn, cs; sincosf(ps, &sn, &cs);
            float v0, v1, v2;
            if (multi) { v0 = auxp[c] * invc; v1 = auxp[INC + c] * invc; v2 = auxp[2 * INC + c] * invc; }
            else       { v0 = f * cs;         v1 = f * sn;               v2 = f * ps; }
            float nw = v0 * cs + v1 * sn + v2 - f * ps;   // singleton: exact cancel
            nv[j] = nw; s2 += nw; ss2 += nw * nw;
        }
#pragma unroll
        for (int m = 1; m < 16; m <<= 1) { s2 += __shfl_xor(s2, m); ss2 += __shfl_xor(ss2, m); }
        float meanN = s2 * (1.f / 128.f);
        float rstdN = rsqrtf(ss2 * (1.f / 128.f) - meanN * meanN + 1e-6f);
        float ov[8];
#pragma unroll
        for (int j = 0; j < 8; ++j) {
            float nn = (nv[j] - meanN) * rstdN * gn[j] + bn[j];
            float ll = (lv[j] - meanL) * rstdL * gl[j] + bl[j];
            float o = nn + ll;
            ov[j] = o > 0.f ? o : 0.f;
        }
        float4* op = (float4*)(out + (size_t)p * INC + c0);
        op[0] = ((float4*)ov)[0];
        op[1] = ((float4*)ov)[1];
    }
}

// ---------------- host launcher ---------------------------------------------
extern "C" void kernel_launch(void* const* d_in, const int* in_sizes, int n_in,
                              void* d_out, int out_size, void* d_ws, size_t ws_size,
                              hipStream_t stream) {
    (void)in_sizes; (void)n_in; (void)out_size; (void)ws_size;
    const float* F        = (const float*)d_in[0];
    const int*   coords   = (const int*)d_in[1];
    const int*   nbr      = (const int*)d_in[2];
    const int*   aux_idx  = (const int*)d_in[3];
    const float* counts_v = (const float*)d_in[4];
    const float* alpha    = (const float*)d_in[6];
    const float* w_pos    = (const float*)d_in[7];
    const float* w_pre    = (const float*)d_in[8];
    const float* g_pre    = (const float*)d_in[9];
    const float* b_pre    = (const float*)d_in[10];
    const float* w_conv   = (const float*)d_in[11];
    const float* g_local  = (const float*)d_in[12];
    const float* b_local  = (const float*)d_in[13];
    const float* g_norm   = (const float*)d_in[14];
    const float* b_norm   = (const float*)d_in[15];
    float* out = (float*)d_out;

    char* ws = (char*)d_ws;
    __hip_bfloat16* Wp   = (__hip_bfloat16*)(ws + OFF_WP);
    __hip_bfloat16* Wpre = (__hip_bfloat16*)(ws + OFF_WPRE);
    __hip_bfloat16* F_input = (__hip_bfloat16*)(ws + OFF_FIN);
    __hip_bfloat16* loc     = (__hip_bfloat16*)(ws + OFF_LOC);
    int*   rmp   = (int*)(ws + OFF_RMP);
    int*   rmp2  = (int*)(ws + OFF_RMP2);
    float* auxc  = (float*)(ws + OFF_AUXC);
    float* spacc = (float*)(ws + OFF_SPC);
    int*   cnt   = (int*)(ws + OFF_CNT);
    int*   dstb  = (int*)(ws + OFF_DST);
    int*   srcb  = (int*)(ws + OFF_SRC);

    const int mt = (N_PTS + 127) / 128;   // 782
    const int prep_tot = 16384 + NSLOT * 16384;   // 458,752 (>= N_PTS)
    k_prep<<<(prep_tot + 255) / 256, 256, 0, stream>>>(w_pre, w_conv, Wp, Wpre, rmp, rmp2, cnt);
    k_scan<<<(N_PTS + 255) / 256, 256, 0, stream>>>(nbr, counts_v, aux_idx, rmp, rmp2, cnt, dstb, srcb);
    k_assign<<<(N_PTS + 255) / 256, 256, 0, stream>>>(rmp, rmp2, cnt, auxc, spacc);
    k_pre_gemm<<<mt, 256, 0, stream>>>(F, Wpre, Wp, coords, counts_v, aux_idx, rmp,
                                       w_pos, alpha, g_pre, b_pre, F_input, loc, auxc);
    k_sparse<<<26 * 128, 64, 0, stream>>>(F, Wp, cnt, dstb, srcb, rmp2, spacc);
    k_final<<<mt, 256, 0, stream>>>(F_input, loc, rmp, rmp2, auxc, spacc, coords, counts_v,
                                    aux_idx, w_pos, alpha, g_local, b_local, g_norm, b_norm, out);
}

// Round 7
// 498.557 us; speedup vs baseline: 1.0823x; 1.0090x over previous
//
#include <hip/hip_runtime.h>
#include <hip/hip_bf16.h>
#include <stdint.h>

#define N_PTS 100000
#define INC 128
#define NSLOT 27

typedef float f32x4 __attribute__((ext_vector_type(4)));
typedef short bf16x8 __attribute__((ext_vector_type(8)));

// ---------------- workspace layout --------------------------------------
static const size_t OFF_WP   = 0;                                        // 27 slots frag-packed bf16
static const size_t SZ_WP    = (size_t)NSLOT * INC * INC * 2;
static const size_t OFF_WPRE = (OFF_WP + SZ_WP + 255) & ~(size_t)255;    // w_pre frag-packed bf16
static const size_t SZ_WPRE  = (size_t)INC * INC * 2;
static const size_t OFF_FIN  = (OFF_WPRE + SZ_WPRE + 255) & ~(size_t)255; // F_input bf16
static const size_t SZ_FIN   = (size_t)N_PTS * INC * 2;
static const size_t OFF_LNL  = (OFF_FIN + SZ_FIN + 255) & ~(size_t)255;   // LN(local) bf16
static const size_t SZ_LNL   = (size_t)N_PTS * INC * 2;
static const size_t OFF_AUX  = (OFF_LNL + SZ_LNL + 255) & ~(size_t)255;   // aux rows f32 (by aux_idx)
static const size_t SZ_AUX   = (size_t)N_PTS * 3 * INC * 4;  // total ~206 MB

__device__ __forceinline__ float compute_pos3(float w0, float w1, float w2, float a,
                                              float cx, float cy, float cz) {
    return (cx * w0 + cy * w1 + cz * w2) * a;
}

// load 8 consecutive f32 and round to a bf16x8 MFMA fragment
__device__ __forceinline__ bf16x8 ld_cvt8(const float* __restrict__ p) {
    const float4 u = *(const float4*)p;
    const float4 v = *(const float4*)(p + 4);
    bf16x8 r;
    __hip_bfloat16* h = (__hip_bfloat16*)&r;
    h[0] = __float2bfloat16(u.x); h[1] = __float2bfloat16(u.y);
    h[2] = __float2bfloat16(u.z); h[3] = __float2bfloat16(u.w);
    h[4] = __float2bfloat16(v.x); h[5] = __float2bfloat16(v.y);
    h[6] = __float2bfloat16(v.z); h[7] = __float2bfloat16(v.w);
    return r;
}

__device__ __forceinline__ float sel4(f32x4 v, int r) {
    return r == 0 ? v[0] : r == 1 ? v[1] : r == 2 ? v[2] : v[3];
}

// ---------------- K_prep: pack weights into MFMA fragment order -------------
// lane (q=lane>>4,l15=lane&15) of frag (slot,ks,j) holds B[n=j*16+l15][k=ks*32+q*8+i]
__global__ __launch_bounds__(256) void k_prep(
        const float* __restrict__ w_pre, const float* __restrict__ w_conv,
        __hip_bfloat16* __restrict__ Wp, __hip_bfloat16* __restrict__ Wpre) {
    int i = blockIdx.x * 256 + threadIdx.x;
    if (i < 16384) {                      // w_pre pack: B[n=d][k=c] = w_pre[d][c]
        int j = i;
        int ii = j & 7, lane = (j >> 3) & 63, jj = (j >> 9) & 7, ks = (j >> 12) & 3;
        int l15 = lane & 15, qq = lane >> 4;
        int d = jj * 16 + l15, c = ks * 32 + qq * 8 + ii;
        Wpre[j] = __float2bfloat16(w_pre[d * INC + c]);
    } else if (i < 16384 + NSLOT * 16384) {  // w_conv pack: B[n=d][k=c] = w_conv[slot][c][d]
        int j = i - 16384;
        int ii = j & 7, lane = (j >> 3) & 63, jj = (j >> 9) & 7, ks = (j >> 12) & 3;
        int slot = j >> 14;
        int l15 = lane & 15, qq = lane >> 4;
        int c = ks * 32 + qq * 8 + ii, d = jj * 16 + l15;
        Wp[j] = __float2bfloat16(w_conv[(size_t)slot * INC * INC + (size_t)c * INC + d]);
    }
}

// ---------------- K_zero: zero aux rows of multi-member cells ---------------
__global__ __launch_bounds__(256) void k_zero(
        const float* __restrict__ counts_v, const int* __restrict__ aux_idx,
        float* __restrict__ aux) {
    int p = blockIdx.x * 256 + threadIdx.x;
    if (p >= N_PTS) return;
    if (counts_v[p] > 1.5f) {
        float4* row = (float4*)(aux + (size_t)aux_idx[p] * (3 * INC));
#pragma unroll
        for (int i = 0; i < (3 * INC) / 4; ++i) row[i] = make_float4(0.f, 0.f, 0.f, 0.f);
    }
}

// ---------------- K_main: dual GEMM + in-tile sparse conv + both LNs --------
__global__ __launch_bounds__(256) void k_main(
        const float* __restrict__ F, const __hip_bfloat16* __restrict__ Wpre,
        const __hip_bfloat16* __restrict__ Wp, const int* __restrict__ nbr_idx,
        const int* __restrict__ coords, const float* __restrict__ counts_v,
        const int* __restrict__ aux_idx, const float* __restrict__ w_pos,
        const float* __restrict__ alpha, const float* __restrict__ g_pre,
        const float* __restrict__ b_pre, const float* __restrict__ g_local,
        const float* __restrict__ b_local, __hip_bfloat16* __restrict__ F_input,
        __hip_bfloat16* __restrict__ lnloc, float* __restrict__ aux) {
    __shared__ __hip_bfloat16 s_st[4][32][136];   // per-wave transpose buffer (+pad)
    __shared__ float s_gp[INC], s_bp[INC], s_gl[INC], s_bl[INC];
    __shared__ int s_pairs[128 * 26];             // worst-case exact
    __shared__ int s_cnt;

    const int tid = threadIdx.x, w = tid >> 6, lane = tid & 63;
    const int q = lane >> 4, l15 = lane & 15;
    const int p0 = blockIdx.x * 128;

    if (tid == 0) s_cnt = 0;
    if (tid < INC) {
        s_gp[tid] = g_pre[tid];   s_bp[tid] = b_pre[tid];
        s_gl[tid] = g_local[tid]; s_bl[tid] = b_local[tid];
    }
    __syncthreads();

    // ---- build in-tile pair list (dst-local, slot, src) --------------------
    for (int e = tid; e < 128 * NSLOT; e += 256) {
        int pl = e / NSLOT, k = e - pl * NSLOT;
        if (k == 13) continue;                    // self handled densely
        int p = p0 + pl;
        if (p >= N_PTS) continue;
        int m = nbr_idx[(size_t)p * NSLOT + k];
        if (m < N_PTS) {
            int idx = atomicAdd(&s_cnt, 1);
            s_pairs[idx] = (m << 12) | (pl << 5) | k;
        }
    }

    // ---- dense dual GEMM: pre_mix + self-slot conv --------------------------
    int grow0 = p0 + (w << 5) + l15;
    int grow1 = grow0 + 16;
    if (grow0 >= N_PTS) grow0 = N_PTS - 1;   // clamp; stores are guarded
    if (grow1 >= N_PTS) grow1 = N_PTS - 1;

    const float* A0 = F + (size_t)grow0 * INC + q * 8;
    const float* A1 = F + (size_t)grow1 * INC + q * 8;
    const bf16x8* BpP = (const bf16x8*)Wpre;
    const bf16x8* BpL = (const bf16x8*)Wp + (size_t)13 * 2048;   // self slot

    f32x4 accP[2][8], accL[2][8];
#pragma unroll
    for (int i = 0; i < 2; ++i)
#pragma unroll
        for (int j = 0; j < 8; ++j) {
            accP[i][j] = (f32x4){0.f, 0.f, 0.f, 0.f};
            accL[i][j] = (f32x4){0.f, 0.f, 0.f, 0.f};
        }

#pragma unroll
    for (int ks = 0; ks < 4; ++ks) {
        bf16x8 a0 = ld_cvt8(A0 + ks * 32);
        bf16x8 a1 = ld_cvt8(A1 + ks * 32);
        bf16x8 bP[8], bL[8];
#pragma unroll
        for (int j = 0; j < 8; ++j) { bP[j] = BpP[(ks * 8 + j) * 64 + lane]; bL[j] = BpL[(ks * 8 + j) * 64 + lane]; }
#pragma unroll
        for (int j = 0; j < 8; ++j) {
            accP[0][j] = __builtin_amdgcn_mfma_f32_16x16x32_bf16(a0, bP[j], accP[0][j], 0, 0, 0);
            accP[1][j] = __builtin_amdgcn_mfma_f32_16x16x32_bf16(a1, bP[j], accP[1][j], 0, 0, 0);
            accL[0][j] = __builtin_amdgcn_mfma_f32_16x16x32_bf16(a0, bL[j], accL[0][j], 0, 0, 0);
            accL[1][j] = __builtin_amdgcn_mfma_f32_16x16x32_bf16(a1, bL[j], accL[1][j], 0, 0, 0);
        }
    }
    __syncthreads();   // pair list complete

    // ---- LN_pre epilogue: F_input bf16 (via LDS transpose) + aux atomics ----
#pragma unroll
    for (int i = 0; i < 2; ++i) {
#pragma unroll
        for (int r = 0; r < 4; ++r) {
            int ri = (i << 4) + (q << 2) + r;
            int p = p0 + (w << 5) + ri;
            float vj[8], s = 0.f, ss = 0.f;
#pragma unroll
            for (int j = 0; j < 8; ++j) { float v = accP[i][j][r]; vj[j] = v; s += v; ss += v * v; }
#pragma unroll
            for (int m = 1; m < 16; m <<= 1) { s += __shfl_xor(s, m); ss += __shfl_xor(ss, m); }
            float mean = s * (1.f / 128.f);
            float rstd = rsqrtf(ss * (1.f / 128.f) - mean * mean + 1e-6f);
            bool multi = p < N_PTS && counts_v[p] > 1.5f;
            float cx = 0.f, cy = 0.f, cz = 0.f;
            float* auxp = aux;
            if (multi) {
                cx = (float)coords[p * 3 + 0]; cy = (float)coords[p * 3 + 1];
                cz = (float)coords[p * 3 + 2];
                auxp = aux + (size_t)aux_idx[p] * (3 * INC);
            }
#pragma unroll
            for (int j = 0; j < 8; ++j) {
                int c = (j << 4) + l15;
                float fi = (vj[j] - mean) * rstd * s_gp[c] + s_bp[c];
                __hip_bfloat16 fb = __float2bfloat16(fi);
                s_st[w][ri][c] = fb;
                if (multi) {
                    float fr = __bfloat162float(fb);
                    const float* wp = w_pos + c * 3;
                    float ps = compute_pos3(wp[0], wp[1], wp[2], alpha[c], cx, cy, cz);
                    float sn, cs; sincosf(ps, &sn, &cs);
                    atomicAdd(auxp + c,           fr * cs);
                    atomicAdd(auxp + INC + c,     fr * sn);
                    atomicAdd(auxp + 2 * INC + c, fr * ps);
                }
            }
        }
    }
#pragma unroll
    for (int t = 0; t < 8; ++t) {
        int row = (t << 2) + q;
        int p = p0 + (w << 5) + row;
        if (p < N_PTS) {
            bf16x8 v = *(const bf16x8*)&s_st[w][row][l15 * 8];
            *(bf16x8*)(F_input + (size_t)p * INC + l15 * 8) = v;
        }
    }

    // ---- sparse neighbor conv: one broadcast-A MFMA matvec per pair --------
    const int L = s_cnt;
#pragma unroll 1
    for (int t = 0; t < L; ++t) {
        int e = s_pairs[t];                       // broadcast LDS read
        int pl = (e >> 5) & 127;
        if ((pl >> 5) != w) continue;             // wave-uniform skip
        int k = e & 31;
        int m = e >> 12;
        int i_p = (pl >> 4) & 1, q_p = (pl >> 2) & 3, r_p = pl & 3;
        const bf16x8* Bs = (const bf16x8*)Wp + (size_t)k * 2048;
        f32x4 d0[4], d1[4];
#pragma unroll
        for (int j4 = 0; j4 < 4; ++j4) { d0[j4] = (f32x4){0.f,0.f,0.f,0.f}; d1[j4] = (f32x4){0.f,0.f,0.f,0.f}; }
#pragma unroll
        for (int ks = 0; ks < 4; ++ks) {
            bf16x8 av = ld_cvt8(F + (size_t)m * INC + ks * 32 + q * 8);  // broadcast row m
#pragma unroll
            for (int j4 = 0; j4 < 4; ++j4) {
                d0[j4] = __builtin_amdgcn_mfma_f32_16x16x32_bf16(av, Bs[(ks * 8 + j4) * 64 + lane],     d0[j4], 0, 0, 0);
                d1[j4] = __builtin_amdgcn_mfma_f32_16x16x32_bf16(av, Bs[(ks * 8 + 4 + j4) * 64 + lane], d1[j4], 0, 0, 0);
            }
        }
        float dv[8];
#pragma unroll
        for (int j4 = 0; j4 < 4; ++j4) { dv[j4] = sel4(d0[j4], r_p); dv[4 + j4] = sel4(d1[j4], r_p); }
        bool mine = (q == q_p);
#pragma unroll
        for (int j = 0; j < 8; ++j) if (!mine) dv[j] = 0.f;
#define ACC_ADD(I, R) { _Pragma("unroll") for (int j = 0; j < 8; ++j) accL[I][j][R] += dv[j]; }
        if (i_p == 0) {
            switch (r_p) { case 0: ACC_ADD(0,0); break; case 1: ACC_ADD(0,1); break;
                           case 2: ACC_ADD(0,2); break; default: ACC_ADD(0,3); }
        } else {
            switch (r_p) { case 0: ACC_ADD(1,0); break; case 1: ACC_ADD(1,1); break;
                           case 2: ACC_ADD(1,2); break; default: ACC_ADD(1,3); }
        }
#undef ACC_ADD
    }

    // ---- LN_local epilogue -> lnloc bf16 (via LDS transpose) ----------------
#pragma unroll
    for (int i = 0; i < 2; ++i) {
#pragma unroll
        for (int r = 0; r < 4; ++r) {
            int ri = (i << 4) + (q << 2) + r;
            float vj[8], s = 0.f, ss = 0.f;
#pragma unroll
            for (int j = 0; j < 8; ++j) { float v = accL[i][j][r]; vj[j] = v; s += v; ss += v * v; }
#pragma unroll
            for (int m = 1; m < 16; m <<= 1) { s += __shfl_xor(s, m); ss += __shfl_xor(ss, m); }
            float mean = s * (1.f / 128.f);
            float rstd = rsqrtf(ss * (1.f / 128.f) - mean * mean + 1e-6f);
#pragma unroll
            for (int j = 0; j < 8; ++j) {
                int c = (j << 4) + l15;
                s_st[w][ri][c] = __float2bfloat16((vj[j] - mean) * rstd * s_gl[c] + s_bl[c]);
            }
        }
    }
#pragma unroll
    for (int t = 0; t < 8; ++t) {
        int row = (t << 2) + q;
        int p = p0 + (w << 5) + row;
        if (p < N_PTS) {
            bf16x8 v = *(const bf16x8*)&s_st[w][row][l15 * 8];
            *(bf16x8*)(lnloc + (size_t)p * INC + l15 * 8) = v;
        }
    }
}

// ---------------- K_final: streaming epilogue -------------------------------
__global__ __launch_bounds__(256) void k_final(
        const __hip_bfloat16* __restrict__ F_input, const __hip_bfloat16* __restrict__ lnloc,
        const float* __restrict__ aux, const int* __restrict__ coords,
        const float* __restrict__ counts_v, const int* __restrict__ aux_idx,
        const float* __restrict__ w_pos, const float* __restrict__ alpha,
        const float* __restrict__ g_norm, const float* __restrict__ b_norm,
        float* __restrict__ out) {
    const int tid = threadIdx.x, g = tid >> 4, l15 = tid & 15;
    const int c0 = l15 * 8;
    const int p0 = blockIdx.x * 128;

    float wpv[24], pa[8], gn[8], bn[8];
#pragma unroll
    for (int t = 0; t < 6; ++t) ((float4*)wpv)[t] = ((const float4*)(w_pos + c0 * 3))[t];
#pragma unroll
    for (int t = 0; t < 2; ++t) {
        ((float4*)pa)[t] = ((const float4*)(alpha  + c0))[t];
        ((float4*)gn)[t] = ((const float4*)(g_norm + c0))[t];
        ((float4*)bn)[t] = ((const float4*)(b_norm + c0))[t];
    }

#pragma unroll 1
    for (int t = 0; t < 8; ++t) {
        int p = p0 + t * 16 + g;
        if (p >= N_PTS) continue;

        float cnt = counts_v[p];
        bool multi = cnt > 1.5f;
        float invc = 1.f / cnt;
        float cx = (float)coords[p * 3 + 0], cy = (float)coords[p * 3 + 1],
              cz = (float)coords[p * 3 + 2];
        const float* auxp = aux + (size_t)aux_idx[p] * (3 * INC);

        bf16x8 fbv = *(const bf16x8*)(F_input + (size_t)p * INC + c0);
        float nv[8], s2 = 0.f, ss2 = 0.f;
#pragma unroll
        for (int j = 0; j < 8; ++j) {
            int c = c0 + j;
            float f = __bfloat162float(((__hip_bfloat16*)&fbv)[j]);
            float ps = compute_pos3(wpv[j * 3], wpv[j * 3 + 1], wpv[j * 3 + 2], pa[j], cx, cy, cz);
            float sn, cs; sincosf(ps, &sn, &cs);
            float v0, v1, v2;
            if (multi) { v0 = auxp[c] * invc; v1 = auxp[INC + c] * invc; v2 = auxp[2 * INC + c] * invc; }
            else       { v0 = f * cs;         v1 = f * sn;               v2 = f * ps; }
            float nw = v0 * cs + v1 * sn + v2 - f * ps;   // singleton: exact cancel
            nv[j] = nw; s2 += nw; ss2 += nw * nw;
        }
#pragma unroll
        for (int m = 1; m < 16; m <<= 1) { s2 += __shfl_xor(s2, m); ss2 += __shfl_xor(ss2, m); }
        float meanN = s2 * (1.f / 128.f);
        float rstdN = rsqrtf(ss2 * (1.f / 128.f) - meanN * meanN + 1e-6f);

        bf16x8 lb = *(const bf16x8*)(lnloc + (size_t)p * INC + c0);
        float ov[8];
#pragma unroll
        for (int j = 0; j < 8; ++j) {
            float nn = (nv[j] - meanN) * rstdN * gn[j] + bn[j];
            float o = nn + __bfloat162float(((__hip_bfloat16*)&lb)[j]);
            ov[j] = o > 0.f ? o : 0.f;
        }
        float4* op = (float4*)(out + (size_t)p * INC + c0);
        op[0] = ((float4*)ov)[0];
        op[1] = ((float4*)ov)[1];
    }
}

// ---------------- host launcher ---------------------------------------------
extern "C" void kernel_launch(void* const* d_in, const int* in_sizes, int n_in,
                              void* d_out, int out_size, void* d_ws, size_t ws_size,
                              hipStream_t stream) {
    (void)in_sizes; (void)n_in; (void)out_size; (void)ws_size;
    const float* F        = (const float*)d_in[0];
    const int*   coords   = (const int*)d_in[1];
    const int*   nbr      = (const int*)d_in[2];
    const int*   aux_idx  = (const int*)d_in[3];
    const float* counts_v = (const float*)d_in[4];
    const float* alpha    = (const float*)d_in[6];
    const float* w_pos    = (const float*)d_in[7];
    const float* w_pre    = (const float*)d_in[8];
    const float* g_pre    = (const float*)d_in[9];
    const float* b_pre    = (const float*)d_in[10];
    const float* w_conv   = (const float*)d_in[11];
    const float* g_local  = (const float*)d_in[12];
    const float* b_local  = (const float*)d_in[13];
    const float* g_norm   = (const float*)d_in[14];
    const float* b_norm   = (const float*)d_in[15];
    float* out = (float*)d_out;

    char* ws = (char*)d_ws;
    __hip_bfloat16* Wp      = (__hip_bfloat16*)(ws + OFF_WP);
    __hip_bfloat16* Wpre    = (__hip_bfloat16*)(ws + OFF_WPRE);
    __hip_bfloat16* F_input = (__hip_bfloat16*)(ws + OFF_FIN);
    __hip_bfloat16* lnloc   = (__hip_bfloat16*)(ws + OFF_LNL);
    float*          aux     = (float*)(ws + OFF_AUX);

    const int mt = (N_PTS + 127) / 128;           // 782
    const int prep_tot = 16384 + NSLOT * 16384;   // 458,752
    k_prep<<<(prep_tot + 255) / 256, 256, 0, stream>>>(w_pre, w_conv, Wp, Wpre);
    k_zero<<<(N_PTS + 255) / 256, 256, 0, stream>>>(counts_v, aux_idx, aux);
    k_main<<<mt, 256, 0, stream>>>(F, Wpre, Wp, nbr, coords, counts_v, aux_idx,
                                   w_pos, alpha, g_pre, b_pre, g_local, b_local,
                                   F_input, lnloc, aux);
    k_final<<<mt, 256, 0, stream>>>(F_input, lnloc, aux, coords, counts_v, aux_idx,
                                    w_pos, alpha, g_norm, b_norm, out);
}

// Round 8
// 378.565 us; speedup vs baseline: 1.4254x; 1.3170x over previous
//
#include <hip/hip_runtime.h>
#include <hip/hip_bf16.h>
#include <stdint.h>

#define N_PTS 100000
#define INC 128
#define NSLOT 27
#define CAPP 8192                 // pairs per slot-bucket (expected ~620)

typedef float f32x4 __attribute__((ext_vector_type(4)));
typedef short bf16x8 __attribute__((ext_vector_type(8)));

// ---------------- workspace layout --------------------------------------
static const size_t OFF_WP   = 0;                                        // 27 slots frag-packed bf16
static const size_t SZ_WP    = (size_t)NSLOT * INC * INC * 2;
static const size_t OFF_WPRE = (OFF_WP + SZ_WP + 255) & ~(size_t)255;    // w_pre frag-packed bf16
static const size_t SZ_WPRE  = (size_t)INC * INC * 2;
static const size_t OFF_FIN  = (OFF_WPRE + SZ_WPRE + 255) & ~(size_t)255; // F_input bf16
static const size_t SZ_FIN   = (size_t)N_PTS * INC * 2;
static const size_t OFF_LOC  = (OFF_FIN + SZ_FIN + 255) & ~(size_t)255;   // local accum f32
static const size_t SZ_LOC   = (size_t)N_PTS * INC * 4;
static const size_t OFF_AUX  = (OFF_LOC + SZ_LOC + 255) & ~(size_t)255;   // aux rows f32 (by aux_idx)
static const size_t SZ_AUX   = (size_t)N_PTS * 3 * INC * 4;
static const size_t OFF_CNT  = (OFF_AUX + SZ_AUX + 255) & ~(size_t)255;   // 26 bucket counters
static const size_t SZ_CNT   = 128;
static const size_t OFF_DST  = (OFF_CNT + SZ_CNT + 255) & ~(size_t)255;
static const size_t SZ_DST   = (size_t)26 * CAPP * 4;
static const size_t OFF_SRC  = (OFF_DST + SZ_DST + 255) & ~(size_t)255;
static const size_t SZ_SRC   = (size_t)26 * CAPP * 4;   // total ~234 MB

__device__ __forceinline__ float compute_pos3(float w0, float w1, float w2, float a,
                                              float cx, float cy, float cz) {
    return (cx * w0 + cy * w1 + cz * w2) * a;
}

// load 8 consecutive f32 and round to a bf16x8 MFMA fragment
__device__ __forceinline__ bf16x8 ld_cvt8(const float* __restrict__ p) {
    const float4 u = *(const float4*)p;
    const float4 v = *(const float4*)(p + 4);
    bf16x8 r;
    __hip_bfloat16* h = (__hip_bfloat16*)&r;
    h[0] = __float2bfloat16(u.x); h[1] = __float2bfloat16(u.y);
    h[2] = __float2bfloat16(u.z); h[3] = __float2bfloat16(u.w);
    h[4] = __float2bfloat16(v.x); h[5] = __float2bfloat16(v.y);
    h[6] = __float2bfloat16(v.z); h[7] = __float2bfloat16(v.w);
    return r;
}

#define PREP_BLOCKS 1792   // 458752 threads for weight packing
#define SCAN_BLOCKS 391    // 100096 threads for scan

// ---------------- K_setup: pack weights | scan pairs + zero multi aux -------
__global__ __launch_bounds__(256) void k_setup(
        const float* __restrict__ w_pre, const float* __restrict__ w_conv,
        const int* __restrict__ nbr_idx, const float* __restrict__ counts_v,
        const int* __restrict__ aux_idx,
        __hip_bfloat16* __restrict__ Wp, __hip_bfloat16* __restrict__ Wpre,
        float* __restrict__ aux, int* __restrict__ cnt,
        int* __restrict__ dst, int* __restrict__ src) {
    const int bid = blockIdx.x, tid = threadIdx.x;
    if (bid < PREP_BLOCKS) {
        int i = bid * 256 + tid;
        if (i < 16384) {                      // w_pre pack: B[n=d][k=c] = w_pre[d][c]
            int j = i;
            int ii = j & 7, lane = (j >> 3) & 63, jj = (j >> 9) & 7, ks = (j >> 12) & 3;
            int l15 = lane & 15, qq = lane >> 4;
            int d = jj * 16 + l15, c = ks * 32 + qq * 8 + ii;
            Wpre[j] = __float2bfloat16(w_pre[d * INC + c]);
        } else if (i < 16384 + NSLOT * 16384) {  // w_conv pack: B[n=d][k=c] = w_conv[slot][c][d]
            int j = i - 16384;
            int ii = j & 7, lane = (j >> 3) & 63, jj = (j >> 9) & 7, ks = (j >> 12) & 3;
            int slot = j >> 14;
            int l15 = lane & 15, qq = lane >> 4;
            int c = ks * 32 + qq * 8 + ii, d = jj * 16 + l15;
            Wp[j] = __float2bfloat16(w_conv[(size_t)slot * INC * INC + (size_t)c * INC + d]);
        }
        return;
    }
    // scan part
    const int p = (bid - PREP_BLOCKS) * 256 + tid;
    const int lane = tid & 63;
    const bool vp = p < N_PTS;
    if (vp && counts_v[p] > 1.5f) {           // zero this point's cell aux row (idempotent)
        float4* row = (float4*)(aux + (size_t)aux_idx[p] * (3 * INC));
#pragma unroll
        for (int i = 0; i < (3 * INC) / 4; ++i) row[i] = make_float4(0.f, 0.f, 0.f, 0.f);
    }
    const int* nb = nbr_idx + (size_t)p * NSLOT;
#pragma unroll 1
    for (int k = 0; k < NSLOT; ++k) {
        if (k == 13) continue;                // self handled densely
        int m = vp ? nb[k] : N_PTS;
        bool found = m < N_PTS;
        unsigned long long mask = __ballot(found);
        if (mask == 0ull) continue;
        int b = k < 13 ? k : k - 1;           // 0..25
        int total = __popcll(mask);
        int base = 0;
        if (lane == 0) base = atomicAdd(&cnt[b], total);   // one atomic per wave
        base = __shfl(base, 0);
        if (found) {
            int idx = base + __popcll(mask & ((1ull << lane) - 1ull));
            if (idx < CAPP) { dst[b * CAPP + idx] = p; src[b * CAPP + idx] = m; }
        }
    }
}

// ---------------- K_gemm: two sequential GEMMs (pre_mix, self-conv) ---------
__global__ __launch_bounds__(256, 4) void k_gemm(
        const float* __restrict__ F, const __hip_bfloat16* __restrict__ Wpre,
        const __hip_bfloat16* __restrict__ Wp, const int* __restrict__ coords,
        const float* __restrict__ counts_v, const int* __restrict__ aux_idx,
        const float* __restrict__ w_pos, const float* __restrict__ alpha,
        const float* __restrict__ g_pre, const float* __restrict__ b_pre,
        __hip_bfloat16* __restrict__ F_input, float* __restrict__ loc,
        float* __restrict__ aux) {
    __shared__ char s_buf[4][8704];           // per-wave: 32 rows x (136 bf16 | 68 f32)
    __shared__ float s_gp[INC], s_bp[INC];

    const int tid = threadIdx.x, w = tid >> 6, lane = tid & 63;
    const int q = lane >> 4, l15 = lane & 15;
    const int p0 = blockIdx.x * 128;

    if (tid < INC) { s_gp[tid] = g_pre[tid]; s_bp[tid] = b_pre[tid]; }
    __syncthreads();

    int grow0 = p0 + (w << 5) + l15;
    int grow1 = grow0 + 16;
    if (grow0 >= N_PTS) grow0 = N_PTS - 1;    // clamp; stores guarded
    if (grow1 >= N_PTS) grow1 = N_PTS - 1;

    const float* A0 = F + (size_t)grow0 * INC + q * 8;
    const float* A1 = F + (size_t)grow1 * INC + q * 8;

    __hip_bfloat16* s_bf = (__hip_bfloat16*)s_buf[w];   // [32][136]
    float*          s_f  = (float*)s_buf[w];            // [32][68]

    // ================= pass P: pre_mix GEMM =================
    {
        const bf16x8* Bp = (const bf16x8*)Wpre;
        f32x4 acc[2][8];
#pragma unroll
        for (int i = 0; i < 2; ++i)
#pragma unroll
            for (int j = 0; j < 8; ++j) acc[i][j] = (f32x4){0.f, 0.f, 0.f, 0.f};
#pragma unroll
        for (int ks = 0; ks < 4; ++ks) {
            bf16x8 a0 = ld_cvt8(A0 + ks * 32);
            bf16x8 a1 = ld_cvt8(A1 + ks * 32);
#pragma unroll
            for (int j = 0; j < 8; ++j) {
                bf16x8 b = Bp[(ks * 8 + j) * 64 + lane];
                acc[0][j] = __builtin_amdgcn_mfma_f32_16x16x32_bf16(a0, b, acc[0][j], 0, 0, 0);
                acc[1][j] = __builtin_amdgcn_mfma_f32_16x16x32_bf16(a1, b, acc[1][j], 0, 0, 0);
            }
        }
        // LN_pre epilogue -> bf16 LDS + aux atomics (native sin/cos)
#pragma unroll
        for (int i = 0; i < 2; ++i) {
#pragma unroll
            for (int r = 0; r < 4; ++r) {
                int ri = (i << 4) + (q << 2) + r;
                int p = p0 + (w << 5) + ri;
                float vj[8], s = 0.f, ss = 0.f;
#pragma unroll
                for (int j = 0; j < 8; ++j) { float v = acc[i][j][r]; vj[j] = v; s += v; ss += v * v; }
#pragma unroll
                for (int m = 1; m < 16; m <<= 1) { s += __shfl_xor(s, m); ss += __shfl_xor(ss, m); }
                float mean = s * (1.f / 128.f);
                float rstd = rsqrtf(ss * (1.f / 128.f) - mean * mean + 1e-6f);
                bool multi = p < N_PTS && counts_v[p] > 1.5f;
                float cx = 0.f, cy = 0.f, cz = 0.f;
                float* auxp = aux;
                if (multi) {
                    cx = (float)coords[p * 3 + 0]; cy = (float)coords[p * 3 + 1];
                    cz = (float)coords[p * 3 + 2];
                    auxp = aux + (size_t)aux_idx[p] * (3 * INC);
                }
#pragma unroll
                for (int j = 0; j < 8; ++j) {
                    int c = (j << 4) + l15;
                    float fi = (vj[j] - mean) * rstd * s_gp[c] + s_bp[c];
                    __hip_bfloat16 fb = __float2bfloat16(fi);
                    s_bf[ri * 136 + c] = fb;
                    if (multi) {
                        float fr = __bfloat162float(fb);
                        const float* wp = w_pos + c * 3;
                        float ps = compute_pos3(wp[0], wp[1], wp[2], alpha[c], cx, cy, cz);
                        float sn = __sinf(ps), cs = __cosf(ps);
                        atomicAdd(auxp + c,           fr * cs);
                        atomicAdd(auxp + INC + c,     fr * sn);
                        atomicAdd(auxp + 2 * INC + c, fr * ps);
                    }
                }
            }
        }
#pragma unroll
        for (int t = 0; t < 8; ++t) {
            int row = (t << 2) + q;
            int p = p0 + (w << 5) + row;
            if (p < N_PTS) {
                bf16x8 v = *(const bf16x8*)&s_bf[row * 136 + l15 * 8];
                *(bf16x8*)(F_input + (size_t)p * INC + l15 * 8) = v;
            }
        }
    }

    // ================= pass L: self-slot conv GEMM =================
    {
        const bf16x8* Bp = (const bf16x8*)Wp + (size_t)13 * 2048;   // self slot
        f32x4 acc[2][8];
#pragma unroll
        for (int i = 0; i < 2; ++i)
#pragma unroll
            for (int j = 0; j < 8; ++j) acc[i][j] = (f32x4){0.f, 0.f, 0.f, 0.f};
#pragma unroll
        for (int ks = 0; ks < 4; ++ks) {
            bf16x8 a0 = ld_cvt8(A0 + ks * 32);
            bf16x8 a1 = ld_cvt8(A1 + ks * 32);
#pragma unroll
            for (int j = 0; j < 8; ++j) {
                bf16x8 b = Bp[(ks * 8 + j) * 64 + lane];
                acc[0][j] = __builtin_amdgcn_mfma_f32_16x16x32_bf16(a0, b, acc[0][j], 0, 0, 0);
                acc[1][j] = __builtin_amdgcn_mfma_f32_16x16x32_bf16(a1, b, acc[1][j], 0, 0, 0);
            }
        }
        // f32 store via two half-transposes -> full-line 256B bursts
#pragma unroll
        for (int h = 0; h < 2; ++h) {
#pragma unroll
            for (int i = 0; i < 2; ++i)
#pragma unroll
                for (int r = 0; r < 4; ++r) {
                    int ri = (i << 4) + (q << 2) + r;
#pragma unroll
                    for (int j4 = 0; j4 < 4; ++j4)
                        s_f[ri * 68 + j4 * 16 + l15] = acc[i][h * 4 + j4][r];
                }
#pragma unroll
            for (int t = 0; t < 8; ++t) {
                int row = (t << 2) + q;
                int p = p0 + (w << 5) + row;
                if (p < N_PTS) {
                    float4 v = *(const float4*)&s_f[row * 68 + l15 * 4];
                    *(float4*)(loc + (size_t)p * INC + h * 64 + l15 * 4) = v;
                }
            }
        }
    }
}

// ---------------- K_pairs: 16 same-slot pairs per wave, MFMA + scatter ------
__global__ __launch_bounds__(256) void k_pairs(
        const float* __restrict__ F, const __hip_bfloat16* __restrict__ Wp,
        const int* __restrict__ cnt, const int* __restrict__ dst,
        const int* __restrict__ src, float* __restrict__ loc) {
    const int b = blockIdx.x >> 7;            // bucket 0..25 (128 blocks each)
    const int chunk = blockIdx.x & 127;
    int n = cnt[b]; if (n > CAPP) n = CAPP;
    const int wv = threadIdx.x >> 6;
    const int base = chunk * 64 + wv * 16;    // this wave's 16 pairs
    if (base >= n) return;
    const int slot = b < 13 ? b : b + 1;

    const int lane = threadIdx.x & 63;
    const int q = lane >> 4, l15 = lane & 15;
    const int* srcb = src + b * CAPP;
    const int* dstb = dst + b * CAPP;

    int mrow = (base + l15 < n) ? srcb[base + l15] : 0;   // A row per l15
    const bf16x8* Bp = (const bf16x8*)Wp + (size_t)slot * 2048;

    f32x4 acc[8];
#pragma unroll
    for (int j = 0; j < 8; ++j) acc[j] = (f32x4){0.f, 0.f, 0.f, 0.f};

#pragma unroll
    for (int ks = 0; ks < 4; ++ks) {
        bf16x8 a = ld_cvt8(F + (size_t)mrow * INC + ks * 32 + q * 8);
#pragma unroll
        for (int j = 0; j < 8; ++j)
            acc[j] = __builtin_amdgcn_mfma_f32_16x16x32_bf16(a, Bp[(ks * 8 + j) * 64 + lane], acc[j], 0, 0, 0);
    }

    // scatter rows: row m held by lanes q==(m>>2), reg m&3, col l15
#pragma unroll 1
    for (int m = 0; m < 16; ++m) {
        int ri = base + m;
        if (ri >= n) break;
        int d = dstb[ri];
        if (q == (m >> 2)) {
            float* lp = loc + (size_t)d * INC + l15;
            int r = m & 3;
#pragma unroll
            for (int j = 0; j < 8; ++j) atomicAdd(lp + (j << 4), acc[j][r]);
        }
    }
}

// ---------------- K_final: LN(local) + vox + LN(new) + relu -----------------
__global__ __launch_bounds__(256) void k_final(
        const __hip_bfloat16* __restrict__ F_input, const float* __restrict__ loc,
        const float* __restrict__ aux, const int* __restrict__ coords,
        const float* __restrict__ counts_v, const int* __restrict__ aux_idx,
        const float* __restrict__ w_pos, const float* __restrict__ alpha,
        const float* __restrict__ g_local, const float* __restrict__ b_local,
        const float* __restrict__ g_norm, const float* __restrict__ b_norm,
        float* __restrict__ out) {
    const int tid = threadIdx.x, g = tid >> 4, l15 = tid & 15;
    const int c0 = l15 * 8;
    const int p0 = blockIdx.x * 128;

    float wpv[24], pa[8], gl[8], bl[8], gn[8], bn[8];
#pragma unroll
    for (int t = 0; t < 6; ++t) ((float4*)wpv)[t] = ((const float4*)(w_pos + c0 * 3))[t];
#pragma unroll
    for (int t = 0; t < 2; ++t) {
        ((float4*)pa)[t] = ((const float4*)(alpha   + c0))[t];
        ((float4*)gl)[t] = ((const float4*)(g_local + c0))[t];
        ((float4*)bl)[t] = ((const float4*)(b_local + c0))[t];
        ((float4*)gn)[t] = ((const float4*)(g_norm  + c0))[t];
        ((float4*)bn)[t] = ((const float4*)(b_norm  + c0))[t];
    }

#pragma unroll 1
    for (int t = 0; t < 8; ++t) {
        int p = p0 + t * 16 + g;
        if (p >= N_PTS) continue;

        float lv[8], s = 0.f, ss = 0.f;
        ((float4*)lv)[0] = *(const float4*)(loc + (size_t)p * INC + c0);
        ((float4*)lv)[1] = *(const float4*)(loc + (size_t)p * INC + c0 + 4);
#pragma unroll
        for (int j = 0; j < 8; ++j) { s += lv[j]; ss += lv[j] * lv[j]; }
#pragma unroll
        for (int m = 1; m < 16; m <<= 1) { s += __shfl_xor(s, m); ss += __shfl_xor(ss, m); }
        float meanL = s * (1.f / 128.f);
        float rstdL = rsqrtf(ss * (1.f / 128.f) - meanL * meanL + 1e-6f);

        float cnt = counts_v[p];
        bool multi = cnt > 1.5f;
        float invc = 1.f / cnt;
        float cx = (float)coords[p * 3 + 0], cy = (float)coords[p * 3 + 1],
              cz = (float)coords[p * 3 + 2];
        const float* auxp = aux + (size_t)aux_idx[p] * (3 * INC);

        bf16x8 fbv = *(const bf16x8*)(F_input + (size_t)p * INC + c0);
        float nv[8], s2 = 0.f, ss2 = 0.f;
#pragma unroll
        for (int j = 0; j < 8; ++j) {
            int c = c0 + j;
            float f = __bfloat162float(((__hip_bfloat16*)&fbv)[j]);
            float ps = compute_pos3(wpv[j * 3], wpv[j * 3 + 1], wpv[j * 3 + 2], pa[j], cx, cy, cz);
            float sn = __sinf(ps), cs = __cosf(ps);
            float v0, v1, v2;
            if (multi) { v0 = auxp[c] * invc; v1 = auxp[INC + c] * invc; v2 = auxp[2 * INC + c] * invc; }
            else       { v0 = f * cs;         v1 = f * sn;               v2 = f * ps; }
            float nw = v0 * cs + v1 * sn + v2 - f * ps;   // singleton: exact cancel
            nv[j] = nw; s2 += nw; ss2 += nw * nw;
        }
#pragma unroll
        for (int m = 1; m < 16; m <<= 1) { s2 += __shfl_xor(s2, m); ss2 += __shfl_xor(ss2, m); }
        float meanN = s2 * (1.f / 128.f);
        float rstdN = rsqrtf(ss2 * (1.f / 128.f) - meanN * meanN + 1e-6f);
        float ov[8];
#pragma unroll
        for (int j = 0; j < 8; ++j) {
            float nn = (nv[j] - meanN) * rstdN * gn[j] + bn[j];
            float ll = (lv[j] - meanL) * rstdL * gl[j] + bl[j];
            float o = nn + ll;
            ov[j] = o > 0.f ? o : 0.f;
        }
        float4* op = (float4*)(out + (size_t)p * INC + c0);
        op[0] = ((float4*)ov)[0];
        op[1] = ((float4*)ov)[1];
    }
}

// ---------------- host launcher ---------------------------------------------
extern "C" void kernel_launch(void* const* d_in, const int* in_sizes, int n_in,
                              void* d_out, int out_size, void* d_ws, size_t ws_size,
                              hipStream_t stream) {
    (void)in_sizes; (void)n_in; (void)out_size; (void)ws_size;
    const float* F        = (const float*)d_in[0];
    const int*   coords   = (const int*)d_in[1];
    const int*   nbr      = (const int*)d_in[2];
    const int*   aux_idx  = (const int*)d_in[3];
    const float* counts_v = (const float*)d_in[4];
    const float* alpha    = (const float*)d_in[6];
    const float* w_pos    = (const float*)d_in[7];
    const float* w_pre    = (const float*)d_in[8];
    const float* g_pre    = (const float*)d_in[9];
    const float* b_pre    = (const float*)d_in[10];
    const float* w_conv   = (const float*)d_in[11];
    const float* g_local  = (const float*)d_in[12];
    const float* b_local  = (const float*)d_in[13];
    const float* g_norm   = (const float*)d_in[14];
    const float* b_norm   = (const float*)d_in[15];
    float* out = (float*)d_out;

    char* ws = (char*)d_ws;
    __hip_bfloat16* Wp      = (__hip_bfloat16*)(ws + OFF_WP);
    __hip_bfloat16* Wpre    = (__hip_bfloat16*)(ws + OFF_WPRE);
    __hip_bfloat16* F_input = (__hip_bfloat16*)(ws + OFF_FIN);
    float*          loc     = (float*)(ws + OFF_LOC);
    float*          aux     = (float*)(ws + OFF_AUX);
    int*            cnt     = (int*)(ws + OFF_CNT);
    int*            dstb    = (int*)(ws + OFF_DST);
    int*            srcb    = (int*)(ws + OFF_SRC);

    const int mt = (N_PTS + 127) / 128;           // 782
    hipMemsetAsync(cnt, 0, SZ_CNT, stream);
    k_setup<<<PREP_BLOCKS + SCAN_BLOCKS, 256, 0, stream>>>(
        w_pre, w_conv, nbr, counts_v, aux_idx, Wp, Wpre, aux, cnt, dstb, srcb);
    k_gemm<<<mt, 256, 0, stream>>>(F, Wpre, Wp, coords, counts_v, aux_idx,
                                   w_pos, alpha, g_pre, b_pre, F_input, loc, aux);
    k_pairs<<<26 * 128, 256, 0, stream>>>(F, Wp, cnt, dstb, srcb, loc);
    k_final<<<mt, 256, 0, stream>>>(F_input, loc, aux, coords, counts_v, aux_idx,
                                    w_pos, alpha, g_local, b_local, g_norm, b_norm, out);
}

// Round 9
// 277.683 us; speedup vs baseline: 1.9432x; 1.3633x over previous
//
#include <hip/hip_runtime.h>
#include <hip/hip_bf16.h>
#include <stdint.h>

#define N_PTS 100000
#define INC 128
#define NSLOT 27
#define CAPP 8192                 // pairs per slot-bucket (expected ~620)
#define SCAP 64                   // LDS staging cap per slot per block

typedef float f32x4 __attribute__((ext_vector_type(4)));
typedef short bf16x8 __attribute__((ext_vector_type(8)));

// ---------------- workspace layout --------------------------------------
static const size_t OFF_WP   = 0;                                        // 27 slots frag-packed bf16
static const size_t SZ_WP    = (size_t)NSLOT * INC * INC * 2;
static const size_t OFF_WPRE = (OFF_WP + SZ_WP + 255) & ~(size_t)255;    // w_pre frag-packed bf16
static const size_t SZ_WPRE  = (size_t)INC * INC * 2;
static const size_t OFF_FIN  = (OFF_WPRE + SZ_WPRE + 255) & ~(size_t)255; // F_input bf16
static const size_t SZ_FIN   = (size_t)N_PTS * INC * 2;
static const size_t OFF_LOC  = (OFF_FIN + SZ_FIN + 255) & ~(size_t)255;   // local accum f32
static const size_t SZ_LOC   = (size_t)N_PTS * INC * 4;
static const size_t OFF_AUX  = (OFF_LOC + SZ_LOC + 255) & ~(size_t)255;   // aux rows f32 (by aux_idx)
static const size_t SZ_AUX   = (size_t)N_PTS * 3 * INC * 4;
static const size_t OFF_CNT  = (OFF_AUX + SZ_AUX + 255) & ~(size_t)255;   // 26 bucket counters
static const size_t SZ_CNT   = 128;
static const size_t OFF_DST  = (OFF_CNT + SZ_CNT + 255) & ~(size_t)255;
static const size_t SZ_DST   = (size_t)26 * CAPP * 4;
static const size_t OFF_SRC  = (OFF_DST + SZ_DST + 255) & ~(size_t)255;
static const size_t SZ_SRC   = (size_t)26 * CAPP * 4;   // total ~234 MB

__device__ __forceinline__ float compute_pos3(float w0, float w1, float w2, float a,
                                              float cx, float cy, float cz) {
    return (cx * w0 + cy * w1 + cz * w2) * a;
}

// load 8 consecutive f32 and round to a bf16x8 MFMA fragment
__device__ __forceinline__ bf16x8 ld_cvt8(const float* __restrict__ p) {
    const float4 u = *(const float4*)p;
    const float4 v = *(const float4*)(p + 4);
    bf16x8 r;
    __hip_bfloat16* h = (__hip_bfloat16*)&r;
    h[0] = __float2bfloat16(u.x); h[1] = __float2bfloat16(u.y);
    h[2] = __float2bfloat16(u.z); h[3] = __float2bfloat16(u.w);
    h[4] = __float2bfloat16(v.x); h[5] = __float2bfloat16(v.y);
    h[6] = __float2bfloat16(v.z); h[7] = __float2bfloat16(v.w);
    return r;
}

// ---------------- K_prep: pack weights (coalesced source reads) -------------
// packed idx j fields: slot=j>>14, ks=(j>>12)&3, jj=(j>>9)&7, lane=(j>>3)&63, ii=j&7
// holds B[n = jj*16 + (lane&15)][k = ks*32 + (lane>>4)*8 + ii]
__global__ __launch_bounds__(256) void k_prep(
        const float* __restrict__ w_pre, const float* __restrict__ w_conv,
        __hip_bfloat16* __restrict__ Wp, __hip_bfloat16* __restrict__ Wpre) {
    int i = blockIdx.x * 256 + threadIdx.x;
    if (i < 16384) {                        // w_pre: B[n=d][k=c] = w_pre[d*128+c]
        int d = i >> 7, c = i & 127;
        int j = ((c >> 5) << 12) | ((d >> 4) << 9)
              | (((((c >> 3) & 3) << 4) + (d & 15)) << 3) | (c & 7);
        Wpre[j] = __float2bfloat16(w_pre[i]);
    } else if (i < 16384 + NSLOT * 16384) { // w_conv: B[n=d][k=c] = w_conv[slot][c][d]
        int t = i - 16384;
        int slot = t >> 14, rem = t & 16383;
        int c = rem >> 7, d = rem & 127;
        int j = (slot << 14) | ((c >> 5) << 12) | ((d >> 4) << 9)
              | (((((c >> 3) & 3) << 4) + (d & 15)) << 3) | (c & 7);
        Wp[j] = __float2bfloat16(w_conv[t]);
    }
}

// ---------------- K_scan: LDS-staged pair compaction + zero multi aux -------
__global__ __launch_bounds__(256) void k_scan(
        const int* __restrict__ nbr_idx, const float* __restrict__ counts_v,
        const int* __restrict__ aux_idx, float* __restrict__ aux,
        int* __restrict__ cnt, int* __restrict__ dst, int* __restrict__ src) {
    __shared__ int s_cnt[26], s_base[26];
    __shared__ int s_dst[26][SCAP], s_src[26][SCAP];

    const int tid = threadIdx.x;
    const int p = blockIdx.x * 256 + tid;
    const bool vp = p < N_PTS;

    if (tid < 26) s_cnt[tid] = 0;
    __syncthreads();

    if (vp && counts_v[p] > 1.5f) {          // zero this point's cell aux row (idempotent)
        float4* row = (float4*)(aux + (size_t)aux_idx[p] * (3 * INC));
#pragma unroll
        for (int i = 0; i < (3 * INC) / 4; ++i) row[i] = make_float4(0.f, 0.f, 0.f, 0.f);
    }

    const int* nb = nbr_idx + (size_t)p * NSLOT;
#pragma unroll 1
    for (int k = 0; k < NSLOT; ++k) {
        if (k == 13) continue;               // self handled densely
        int m = vp ? nb[k] : N_PTS;
        if (m < N_PTS) {
            int b = k < 13 ? k : k - 1;      // 0..25
            int li = atomicAdd(&s_cnt[b], 1);            // LDS atomic: cheap
            if (li < SCAP) { s_dst[b][li] = p; s_src[b][li] = m; }
            else {                                        // overflow fallback (rare)
                int gi = atomicAdd(&cnt[b], 1);
                if (gi < CAPP) { dst[b * CAPP + gi] = p; src[b * CAPP + gi] = m; }
            }
        }
    }
    __syncthreads();

    // reserve global space: 26 parallel atomics on 26 DIFFERENT addresses
    if (tid < 26) {
        int n = s_cnt[tid]; if (n > SCAP) n = SCAP;
        s_base[tid] = n > 0 ? atomicAdd(&cnt[tid], n) : 0;
        s_cnt[tid] = n;
    }
    __syncthreads();

    // cooperative copy-out (few entries per block)
    for (int b = tid >> 3; b < 26; b += 32) {            // 8 threads per slot
        int n = s_cnt[b], base = s_base[b];
        for (int e = tid & 7; e < n; e += 8) {
            int gi = base + e;
            if (gi < CAPP) { dst[b * CAPP + gi] = s_dst[b][e]; src[b * CAPP + gi] = s_src[b][e]; }
        }
    }
}

// ---------------- K_gemm: two sequential GEMMs (pre_mix, self-conv) ---------
__global__ __launch_bounds__(256, 4) void k_gemm(
        const float* __restrict__ F, const __hip_bfloat16* __restrict__ Wpre,
        const __hip_bfloat16* __restrict__ Wp, const int* __restrict__ coords,
        const float* __restrict__ counts_v, const int* __restrict__ aux_idx,
        const float* __restrict__ w_pos, const float* __restrict__ alpha,
        const float* __restrict__ g_pre, const float* __restrict__ b_pre,
        __hip_bfloat16* __restrict__ F_input, float* __restrict__ loc,
        float* __restrict__ aux) {
    __shared__ char s_buf[4][8704];           // per-wave: 32 rows x (136 bf16 | 68 f32)
    __shared__ float s_gp[INC], s_bp[INC];

    const int tid = threadIdx.x, w = tid >> 6, lane = tid & 63;
    const int q = lane >> 4, l15 = lane & 15;
    const int p0 = blockIdx.x * 128;

    if (tid < INC) { s_gp[tid] = g_pre[tid]; s_bp[tid] = b_pre[tid]; }
    __syncthreads();

    int grow0 = p0 + (w << 5) + l15;
    int grow1 = grow0 + 16;
    if (grow0 >= N_PTS) grow0 = N_PTS - 1;    // clamp; stores guarded
    if (grow1 >= N_PTS) grow1 = N_PTS - 1;

    const float* A0 = F + (size_t)grow0 * INC + q * 8;
    const float* A1 = F + (size_t)grow1 * INC + q * 8;

    __hip_bfloat16* s_bf = (__hip_bfloat16*)s_buf[w];   // [32][136]
    float*          s_f  = (float*)s_buf[w];            // [32][68]

    // ================= pass P: pre_mix GEMM =================
    {
        const bf16x8* Bp = (const bf16x8*)Wpre;
        f32x4 acc[2][8];
#pragma unroll
        for (int i = 0; i < 2; ++i)
#pragma unroll
            for (int j = 0; j < 8; ++j) acc[i][j] = (f32x4){0.f, 0.f, 0.f, 0.f};
#pragma unroll
        for (int ks = 0; ks < 4; ++ks) {
            bf16x8 a0 = ld_cvt8(A0 + ks * 32);
            bf16x8 a1 = ld_cvt8(A1 + ks * 32);
#pragma unroll
            for (int j = 0; j < 8; ++j) {
                bf16x8 b = Bp[(ks * 8 + j) * 64 + lane];
                acc[0][j] = __builtin_amdgcn_mfma_f32_16x16x32_bf16(a0, b, acc[0][j], 0, 0, 0);
                acc[1][j] = __builtin_amdgcn_mfma_f32_16x16x32_bf16(a1, b, acc[1][j], 0, 0, 0);
            }
        }
        // LN_pre epilogue -> bf16 LDS + aux atomics (native sin/cos)
#pragma unroll
        for (int i = 0; i < 2; ++i) {
#pragma unroll
            for (int r = 0; r < 4; ++r) {
                int ri = (i << 4) + (q << 2) + r;
                int p = p0 + (w << 5) + ri;
                float vj[8], s = 0.f, ss = 0.f;
#pragma unroll
                for (int j = 0; j < 8; ++j) { float v = acc[i][j][r]; vj[j] = v; s += v; ss += v * v; }
#pragma unroll
                for (int m = 1; m < 16; m <<= 1) { s += __shfl_xor(s, m); ss += __shfl_xor(ss, m); }
                float mean = s * (1.f / 128.f);
                float rstd = rsqrtf(ss * (1.f / 128.f) - mean * mean + 1e-6f);
                bool multi = p < N_PTS && counts_v[p] > 1.5f;
                float cx = 0.f, cy = 0.f, cz = 0.f;
                float* auxp = aux;
                if (multi) {
                    cx = (float)coords[p * 3 + 0]; cy = (float)coords[p * 3 + 1];
                    cz = (float)coords[p * 3 + 2];
                    auxp = aux + (size_t)aux_idx[p] * (3 * INC);
                }
#pragma unroll
                for (int j = 0; j < 8; ++j) {
                    int c = (j << 4) + l15;
                    float fi = (vj[j] - mean) * rstd * s_gp[c] + s_bp[c];
                    __hip_bfloat16 fb = __float2bfloat16(fi);
                    s_bf[ri * 136 + c] = fb;
                    if (multi) {
                        float fr = __bfloat162float(fb);
                        const float* wp = w_pos + c * 3;
                        float ps = compute_pos3(wp[0], wp[1], wp[2], alpha[c], cx, cy, cz);
                        float sn = __sinf(ps), cs = __cosf(ps);
                        atomicAdd(auxp + c,           fr * cs);
                        atomicAdd(auxp + INC + c,     fr * sn);
                        atomicAdd(auxp + 2 * INC + c, fr * ps);
                    }
                }
            }
        }
#pragma unroll
        for (int t = 0; t < 8; ++t) {
            int row = (t << 2) + q;
            int p = p0 + (w << 5) + row;
            if (p < N_PTS) {
                bf16x8 v = *(const bf16x8*)&s_bf[row * 136 + l15 * 8];
                *(bf16x8*)(F_input + (size_t)p * INC + l15 * 8) = v;
            }
        }
    }

    // ================= pass L: self-slot conv GEMM =================
    {
        const bf16x8* Bp = (const bf16x8*)Wp + (size_t)13 * 2048;   // self slot
        f32x4 acc[2][8];
#pragma unroll
        for (int i = 0; i < 2; ++i)
#pragma unroll
            for (int j = 0; j < 8; ++j) acc[i][j] = (f32x4){0.f, 0.f, 0.f, 0.f};
#pragma unroll
        for (int ks = 0; ks < 4; ++ks) {
            bf16x8 a0 = ld_cvt8(A0 + ks * 32);
            bf16x8 a1 = ld_cvt8(A1 + ks * 32);
#pragma unroll
            for (int j = 0; j < 8; ++j) {
                bf16x8 b = Bp[(ks * 8 + j) * 64 + lane];
                acc[0][j] = __builtin_amdgcn_mfma_f32_16x16x32_bf16(a0, b, acc[0][j], 0, 0, 0);
                acc[1][j] = __builtin_amdgcn_mfma_f32_16x16x32_bf16(a1, b, acc[1][j], 0, 0, 0);
            }
        }
        // f32 store via two half-transposes -> full-line 256B bursts
#pragma unroll
        for (int h = 0; h < 2; ++h) {
#pragma unroll
            for (int i = 0; i < 2; ++i)
#pragma unroll
                for (int r = 0; r < 4; ++r) {
                    int ri = (i << 4) + (q << 2) + r;
#pragma unroll
                    for (int j4 = 0; j4 < 4; ++j4)
                        s_f[ri * 68 + j4 * 16 + l15] = acc[i][h * 4 + j4][r];
                }
#pragma unroll
            for (int t = 0; t < 8; ++t) {
                int row = (t << 2) + q;
                int p = p0 + (w << 5) + row;
                if (p < N_PTS) {
                    float4 v = *(const float4*)&s_f[row * 68 + l15 * 4];
                    *(float4*)(loc + (size_t)p * INC + h * 64 + l15 * 4) = v;
                }
            }
        }
    }
}

// ---------------- K_pairs: 16 same-slot pairs per wave, MFMA + scatter ------
__global__ __launch_bounds__(256) void k_pairs(
        const float* __restrict__ F, const __hip_bfloat16* __restrict__ Wp,
        const int* __restrict__ cnt, const int* __restrict__ dst,
        const int* __restrict__ src, float* __restrict__ loc) {
    const int b = blockIdx.x >> 7;            // bucket 0..25 (128 blocks each)
    const int chunk = blockIdx.x & 127;
    int n = cnt[b]; if (n > CAPP) n = CAPP;
    const int wv = threadIdx.x >> 6;
    const int base = chunk * 64 + wv * 16;    // this wave's 16 pairs
    if (base >= n) return;
    const int slot = b < 13 ? b : b + 1;

    const int lane = threadIdx.x & 63;
    const int q = lane >> 4, l15 = lane & 15;
    const int* srcb = src + b * CAPP;
    const int* dstb = dst + b * CAPP;

    int mrow = (base + l15 < n) ? srcb[base + l15] : 0;   // A row per l15
    const bf16x8* Bp = (const bf16x8*)Wp + (size_t)slot * 2048;

    f32x4 acc[8];
#pragma unroll
    for (int j = 0; j < 8; ++j) acc[j] = (f32x4){0.f, 0.f, 0.f, 0.f};

#pragma unroll
    for (int ks = 0; ks < 4; ++ks) {
        bf16x8 a = ld_cvt8(F + (size_t)mrow * INC + ks * 32 + q * 8);
#pragma unroll
        for (int j = 0; j < 8; ++j)
            acc[j] = __builtin_amdgcn_mfma_f32_16x16x32_bf16(a, Bp[(ks * 8 + j) * 64 + lane], acc[j], 0, 0, 0);
    }

    // scatter rows: row m held by lanes q==(m>>2), reg m&3, col l15
#pragma unroll 1
    for (int m = 0; m < 16; ++m) {
        int ri = base + m;
        if (ri >= n) break;
        int d = dstb[ri];
        if (q == (m >> 2)) {
            float* lp = loc + (size_t)d * INC + l15;
            int r = m & 3;
#pragma unroll
            for (int j = 0; j < 8; ++j) atomicAdd(lp + (j << 4), acc[j][r]);
        }
    }
}

// ---------------- K_final: LN(local) + vox + LN(new) + relu -----------------
__global__ __launch_bounds__(256) void k_final(
        const __hip_bfloat16* __restrict__ F_input, const float* __restrict__ loc,
        const float* __restrict__ aux, const int* __restrict__ coords,
        const float* __restrict__ counts_v, const int* __restrict__ aux_idx,
        const float* __restrict__ w_pos, const float* __restrict__ alpha,
        const float* __restrict__ g_local, const float* __restrict__ b_local,
        const float* __restrict__ g_norm, const float* __restrict__ b_norm,
        float* __restrict__ out) {
    const int tid = threadIdx.x, g = tid >> 4, l15 = tid & 15;
    const int c0 = l15 * 8;
    const int p0 = blockIdx.x * 128;

    float wpv[24], pa[8], gl[8], bl[8], gn[8], bn[8];
#pragma unroll
    for (int t = 0; t < 6; ++t) ((float4*)wpv)[t] = ((const float4*)(w_pos + c0 * 3))[t];
#pragma unroll
    for (int t = 0; t < 2; ++t) {
        ((float4*)pa)[t] = ((const float4*)(alpha   + c0))[t];
        ((float4*)gl)[t] = ((const float4*)(g_local + c0))[t];
        ((float4*)bl)[t] = ((const float4*)(b_local + c0))[t];
        ((float4*)gn)[t] = ((const float4*)(g_norm  + c0))[t];
        ((float4*)bn)[t] = ((const float4*)(b_norm  + c0))[t];
    }

#pragma unroll 1
    for (int t = 0; t < 8; ++t) {
        int p = p0 + t * 16 + g;
        if (p >= N_PTS) continue;

        float lv[8], s = 0.f, ss = 0.f;
        ((float4*)lv)[0] = *(const float4*)(loc + (size_t)p * INC + c0);
        ((float4*)lv)[1] = *(const float4*)(loc + (size_t)p * INC + c0 + 4);
#pragma unroll
        for (int j = 0; j < 8; ++j) { s += lv[j]; ss += lv[j] * lv[j]; }
#pragma unroll
        for (int m = 1; m < 16; m <<= 1) { s += __shfl_xor(s, m); ss += __shfl_xor(ss, m); }
        float meanL = s * (1.f / 128.f);
        float rstdL = rsqrtf(ss * (1.f / 128.f) - meanL * meanL + 1e-6f);

        float cnt = counts_v[p];
        bool multi = cnt > 1.5f;
        float invc = 1.f / cnt;
        float cx = (float)coords[p * 3 + 0], cy = (float)coords[p * 3 + 1],
              cz = (float)coords[p * 3 + 2];
        const float* auxp = aux + (size_t)aux_idx[p] * (3 * INC);

        bf16x8 fbv = *(const bf16x8*)(F_input + (size_t)p * INC + c0);
        float nv[8], s2 = 0.f, ss2 = 0.f;
#pragma unroll
        for (int j = 0; j < 8; ++j) {
            int c = c0 + j;
            float f = __bfloat162float(((__hip_bfloat16*)&fbv)[j]);
            float ps = compute_pos3(wpv[j * 3], wpv[j * 3 + 1], wpv[j * 3 + 2], pa[j], cx, cy, cz);
            float sn = __sinf(ps), cs = __cosf(ps);
            float v0, v1, v2;
            if (multi) { v0 = auxp[c] * invc; v1 = auxp[INC + c] * invc; v2 = auxp[2 * INC + c] * invc; }
            else       { v0 = f * cs;         v1 = f * sn;               v2 = f * ps; }
            float nw = v0 * cs + v1 * sn + v2 - f * ps;   // singleton: exact cancel
            nv[j] = nw; s2 += nw; ss2 += nw * nw;
        }
#pragma unroll
        for (int m = 1; m < 16; m <<= 1) { s2 += __shfl_xor(s2, m); ss2 += __shfl_xor(ss2, m); }
        float meanN = s2 * (1.f / 128.f);
        float rstdN = rsqrtf(ss2 * (1.f / 128.f) - meanN * meanN + 1e-6f);
        float ov[8];
#pragma unroll
        for (int j = 0; j < 8; ++j) {
            float nn = (nv[j] - meanN) * rstdN * gn[j] + bn[j];
            float ll = (lv[j] - meanL) * rstdL * gl[j] + bl[j];
            float o = nn + ll;
            ov[j] = o > 0.f ? o : 0.f;
        }
        float4* op = (float4*)(out + (size_t)p * INC + c0);
        op[0] = ((float4*)ov)[0];
        op[1] = ((float4*)ov)[1];
    }
}

// ---------------- host launcher ---------------------------------------------
extern "C" void kernel_launch(void* const* d_in, const int* in_sizes, int n_in,
                              void* d_out, int out_size, void* d_ws, size_t ws_size,
                              hipStream_t stream) {
    (void)in_sizes; (void)n_in; (void)out_size; (void)ws_size;
    const float* F        = (const float*)d_in[0];
    const int*   coords   = (const int*)d_in[1];
    const int*   nbr      = (const int*)d_in[2];
    const int*   aux_idx  = (const int*)d_in[3];
    const float* counts_v = (const float*)d_in[4];
    const float* alpha    = (const float*)d_in[6];
    const float* w_pos    = (const float*)d_in[7];
    const float* w_pre    = (const float*)d_in[8];
    const float* g_pre    = (const float*)d_in[9];
    const float* b_pre    = (const float*)d_in[10];
    const float* w_conv   = (const float*)d_in[11];
    const float* g_local  = (const float*)d_in[12];
    const float* b_local  = (const float*)d_in[13];
    const float* g_norm   = (const float*)d_in[14];
    const float* b_norm   = (const float*)d_in[15];
    float* out = (float*)d_out;

    char* ws = (char*)d_ws;
    __hip_bfloat16* Wp      = (__hip_bfloat16*)(ws + OFF_WP);
    __hip_bfloat16* Wpre    = (__hip_bfloat16*)(ws + OFF_WPRE);
    __hip_bfloat16* F_input = (__hip_bfloat16*)(ws + OFF_FIN);
    float*          loc     = (float*)(ws + OFF_LOC);
    float*          aux     = (float*)(ws + OFF_AUX);
    int*            cnt     = (int*)(ws + OFF_CNT);
    int*            dstb    = (int*)(ws + OFF_DST);
    int*            srcb    = (int*)(ws + OFF_SRC);

    const int mt = (N_PTS + 127) / 128;           // 782
    hipMemsetAsync(cnt, 0, SZ_CNT, stream);
    k_prep<<<1792, 256, 0, stream>>>(w_pre, w_conv, Wp, Wpre);
    k_scan<<<391, 256, 0, stream>>>(nbr, counts_v, aux_idx, aux, cnt, dstb, srcb);
    k_gemm<<<mt, 256, 0, stream>>>(F, Wpre, Wp, coords, counts_v, aux_idx,
                                   w_pos, alpha, g_pre, b_pre, F_input, loc, aux);
    k_pairs<<<26 * 128, 256, 0, stream>>>(F, Wp, cnt, dstb, srcb, loc);
    k_final<<<mt, 256, 0, stream>>>(F_input, loc, aux, coords, counts_v, aux_idx,
                                    w_pos, alpha, g_local, b_local, g_norm, b_norm, out);
}